// Round 4
// baseline (1331.326 us; speedup 1.0000x reference)
//
#include <hip/hip_runtime.h>
#include <math.h>

#define NPIX 16384      // H*W
#define CCH  512        // channels
#define MS   262144     // 512*512

typedef unsigned short u16;
typedef unsigned int u32;
typedef __attribute__((ext_vector_type(8))) short bf16x8;   // 8 bf16 = 4 VGPR
typedef __attribute__((ext_vector_type(4))) float f32x4;

__device__ __forceinline__ u16 f2bf(float f) {
  u32 u = __builtin_bit_cast(u32, f);
  u += 0x7fffu + ((u >> 16) & 1u);    // round-to-nearest-even
  return (u16)(u >> 16);
}
__device__ __forceinline__ float b2f(u16 h) {
  u32 u = ((u32)h) << 16;
  return __builtin_bit_cast(float, u);
}

typedef const __attribute__((address_space(1))) u32* gp_t;
typedef __attribute__((address_space(3))) u32* lp_t;
__device__ __forceinline__ void gl_lds16(const void* g, void* l) {
  __builtin_amdgcn_global_load_lds((gp_t)g, (lp_t)l, 16, 0, 0);
}

// ---- Kt=64 staged tile (LDS row = 64 bf16 = 8x16B chunks); 8 rows per gl_lds16
__device__ __forceinline__ void stage8_64(const u16* tile, size_t stride, int rl,
                                          int k0, u16* lds, int lane) {
  int lr = lane >> 3;                               // 8 rows per instruction
  int cg2 = (lane & 7) ^ ((rl + lr) & 7);           // swizzled global chunk
  gl_lds16(tile + (size_t)(rl + lr) * stride + k0 + cg2 * 8,
           lds + (size_t)rl * 64);
}
__device__ __forceinline__ bf16x8 fragld64(const u16* lds, int row, int cl) {
  return *(const bf16x8*)&lds[(size_t)row * 64 + (size_t)((cl ^ (row & 7)) << 3)];
}

// ================= prep: one pass over X -> colsums, fct (bf16 [c][n]), fcb (bf16 [n][c])
__global__ __launch_bounds__(256) void prep_k(const float* __restrict__ Xc,
                                              const float* __restrict__ Xs,
                                              float* __restrict__ sums,
                                              u16* __restrict__ fct,
                                              u16* __restrict__ fcb) {
  int b = blockIdx.z;
  const float* X = b ? Xs : Xc;
  u16* outT = fct + (size_t)b * ((size_t)CCH * NPIX);
  __shared__ float T[64][65];
  __shared__ float red2[64][4];
  int n0 = blockIdx.x * 64, c0 = blockIdx.y * 64;
  int t = threadIdx.x;
  int cr = t & 15, nr = t >> 4;
  #pragma unroll
  for (int rr = 0; rr < 4; ++rr) {
    int n = nr + rr * 16;
    float4 v = *(const float4*)&X[(size_t)(n0 + n) * CCH + c0 + cr * 4];
    T[n][cr * 4 + 0] = v.x;
    T[n][cr * 4 + 1] = v.y;
    T[n][cr * 4 + 2] = v.z;
    T[n][cr * 4 + 3] = v.w;
    if (b == 0) {
      ushort4 q;
      q.x = f2bf(v.x); q.y = f2bf(v.y); q.z = f2bf(v.z); q.w = f2bf(v.w);
      *(ushort4*)&fcb[(size_t)(n0 + n) * CCH + c0 + cr * 4] = q;
    }
  }
  __syncthreads();
  int cl = t >> 2, np = (t & 3) * 16;
  size_t obase = (size_t)(c0 + cl) * NPIX + n0 + np;
  float s = 0.f;
  #pragma unroll
  for (int i = 0; i < 16; i += 4) {
    float v0 = T[np + i + 0][cl], v1 = T[np + i + 1][cl];
    float v2 = T[np + i + 2][cl], v3 = T[np + i + 3][cl];
    s += v0 + v1 + v2 + v3;
    ushort4 o;
    o.x = f2bf(v0); o.y = f2bf(v1); o.z = f2bf(v2); o.w = f2bf(v3);
    *(ushort4*)&outT[obase + i] = o;
  }
  red2[cl][t & 3] = s;
  __syncthreads();
  if (t < 64) {
    float cs = red2[t][0] + red2[t][1] + red2[t][2] + red2[t][3];
    atomicAdd(&sums[b * CCH + c0 + t], cs);
  }
}

// ================= Gram partials: 16 pairs x 16 kc x 2 batches = 512 blocks = 2/CU
__global__ __launch_bounds__(256, 2) void gram_part(const u16* __restrict__ fct,
                                                    float* __restrict__ Gp) {
  int kc = blockIdx.x;               // 0..15, K chunk of 1024
  int pair = blockIdx.y;             // 0..15
  int b = blockIdx.z;
  int bi = pair >> 2, bj = pair & 3;
  const u16* Xb = fct + (size_t)b * ((size_t)CCH * NPIX);
  __shared__ u16 As[2][128 * 64];    // 2 x 16 KB
  __shared__ u16 Bs[2][128 * 64];    // 2 x 16 KB
  int tid = threadIdx.x, w = tid >> 6, lane = tid & 63;
  int qm = w & 1, qn = w >> 1;
  const u16* ssrc = (w < 2) ? Xb + (size_t)(bi * 128) * NPIX
                            : Xb + (size_t)(bj * 128) * NPIX;
  int rbase = (w & 1) * 64;
  f32x4 acc[4][4];
  #pragma unroll
  for (int t = 0; t < 4; ++t)
    #pragma unroll
    for (int u = 0; u < 4; ++u) acc[t][u] = (f32x4)(0.f);

  #pragma unroll
  for (int i = 0; i < 8; ++i)
    stage8_64(ssrc, NPIX, rbase + i * 8, kc * 1024, (w < 2) ? As[0] : Bs[0], lane);
  __syncthreads();

  for (int st = 0; st < 16; ++st) {
    int cur = st & 1;
    if (st < 15) {
      int k0n = kc * 1024 + (st + 1) * 64;
      #pragma unroll
      for (int i = 0; i < 8; ++i)
        stage8_64(ssrc, NPIX, rbase + i * 8, k0n,
                  (w < 2) ? As[cur ^ 1] : Bs[cur ^ 1], lane);
    }
    #pragma unroll
    for (int s = 0; s < 2; ++s) {
      int cl = s * 4 + (lane >> 4);
      bf16x8 a[4], bb[4];
      #pragma unroll
      for (int t = 0; t < 4; ++t) a[t] = fragld64(As[cur], qm * 64 + t * 16 + (lane & 15), cl);
      #pragma unroll
      for (int u = 0; u < 4; ++u) bb[u] = fragld64(Bs[cur], qn * 64 + u * 16 + (lane & 15), cl);
      #pragma unroll
      for (int t = 0; t < 4; ++t)
        #pragma unroll
        for (int u = 0; u < 4; ++u)
          acc[t][u] = __builtin_amdgcn_mfma_f32_16x16x32_bf16(a[t], bb[u], acc[t][u], 0, 0, 0);
    }
    __syncthreads();
  }
  size_t tbase = ((size_t)(b * 16 + kc) * 16 + pair) * 16384;
  #pragma unroll
  for (int t = 0; t < 4; ++t) {
    int row0 = qm * 64 + t * 16 + (lane >> 4) * 4;
    #pragma unroll
    for (int u = 0; u < 4; ++u) {
      int col = qn * 64 + u * 16 + (lane & 15);
      #pragma unroll
      for (int r4 = 0; r4 < 4; ++r4)
        Gp[tbase + (size_t)(row0 + r4) * 128 + col] = acc[t][u][r4];
    }
  }
}

// ================= tile workers (64x64 tile, Kt=64 dbuf) =========
// plain: D = diag*I + scale*(A @ B^T); LDS: As@0/4096, Bs@8192/12288 (u16 offs)
__device__ __forceinline__ void mm_step(const u16* A, const u16* B, void* D,
                                        float scale, float diag, int outFp32,
                                        u16* smem, int tid, int bi, int bj) {
  int w = tid >> 6, lane = tid & 63;
  int qm = w & 1, qn = w >> 1;
  const u16* ssrc = (w < 2) ? A + (size_t)(bi * 64) * CCH
                            : B + (size_t)(bj * 64) * CCH;
  int rbase = (w & 1) * 32;
  u16* sbase = (w < 2) ? smem : smem + 8192;
  f32x4 acc[2][2];
  #pragma unroll
  for (int t = 0; t < 2; ++t)
    #pragma unroll
    for (int u = 0; u < 2; ++u) acc[t][u] = (f32x4)(0.f);

  #pragma unroll
  for (int i = 0; i < 4; ++i) stage8_64(ssrc, CCH, rbase + i * 8, 0, sbase, lane);
  __syncthreads();
  for (int st = 0; st < 8; ++st) {
    int cur = st & 1;
    if (st < 7) {
      u16* sdst = sbase + (cur ^ 1) * 4096;
      #pragma unroll
      for (int i = 0; i < 4; ++i) stage8_64(ssrc, CCH, rbase + i * 8, (st + 1) * 64, sdst, lane);
    }
    u16* Ac = smem + cur * 4096;
    u16* Bc = smem + 8192 + cur * 4096;
    #pragma unroll
    for (int s = 0; s < 2; ++s) {
      int cl = s * 4 + (lane >> 4);
      bf16x8 a[2], bb[2];
      #pragma unroll
      for (int t = 0; t < 2; ++t) a[t] = fragld64(Ac, qm * 32 + t * 16 + (lane & 15), cl);
      #pragma unroll
      for (int u = 0; u < 2; ++u) bb[u] = fragld64(Bc, qn * 32 + u * 16 + (lane & 15), cl);
      #pragma unroll
      for (int t = 0; t < 2; ++t)
        #pragma unroll
        for (int u = 0; u < 2; ++u)
          acc[t][u] = __builtin_amdgcn_mfma_f32_16x16x32_bf16(a[t], bb[u], acc[t][u], 0, 0, 0);
    }
    __syncthreads();
  }
  #pragma unroll
  for (int t = 0; t < 2; ++t) {
    int row0 = bi * 64 + qm * 32 + t * 16 + (lane >> 4) * 4;
    #pragma unroll
    for (int u = 0; u < 2; ++u) {
      int col = bj * 64 + qn * 32 + u * 16 + (lane & 15);
      #pragma unroll
      for (int r4 = 0; r4 < 4; ++r4) {
        float v = scale * acc[t][u][r4];
        if (row0 + r4 == col) v += diag;
        size_t o = (size_t)(row0 + r4) * CCH + col;
        if (outFp32) ((float*)D)[o] = v;
        else ((u16*)D)[o] = f2bf(v);
      }
    }
  }
}

// split: uses full 64 KB; array a in {Ah,Al,Bh,Bl} at a*8192 + cur*4096
__device__ __forceinline__ void mms_step(const u16* Ah, const u16* Al,
                                         const u16* Bh, const u16* Bl,
                                         const u16* Eh, const u16* El, float beta,
                                         u16* Dh, u16* Dl, float* D32, u16* Db,
                                         float scale, u16* smem, int tid, int bi, int bj) {
  int w = tid >> 6, lane = tid & 63;
  int qm = w & 1, qn = w >> 1;
  const u16* sp = (w == 0) ? Ah : (w == 1) ? Al : (w == 2) ? Bh : Bl;
  const u16* ssrc = sp + (size_t)(((w < 2) ? bi : bj) * 64) * CCH;
  u16* sbase = smem + w * 8192;
  f32x4 acc[2][2];
  #pragma unroll
  for (int t = 0; t < 2; ++t)
    #pragma unroll
    for (int u = 0; u < 2; ++u) acc[t][u] = (f32x4)(0.f);

  #pragma unroll
  for (int i = 0; i < 8; ++i) stage8_64(ssrc, CCH, i * 8, 0, sbase, lane);
  __syncthreads();
  for (int st = 0; st < 8; ++st) {
    int cur = st & 1;
    if (st < 7) {
      u16* sdst = sbase + (cur ^ 1) * 4096;
      #pragma unroll
      for (int i = 0; i < 8; ++i) stage8_64(ssrc, CCH, i * 8, (st + 1) * 64, sdst, lane);
    }
    u16* Ach = smem + cur * 4096;
    u16* Acl = smem + 8192 + cur * 4096;
    u16* Bch = smem + 16384 + cur * 4096;
    u16* Bcl = smem + 24576 + cur * 4096;
    #pragma unroll
    for (int s = 0; s < 2; ++s) {
      int cl = s * 4 + (lane >> 4);
      bf16x8 ah[2], al[2], bh[2], bl[2];
      #pragma unroll
      for (int t = 0; t < 2; ++t) {
        int row = qm * 32 + t * 16 + (lane & 15);
        ah[t] = fragld64(Ach, row, cl);
        al[t] = fragld64(Acl, row, cl);
      }
      #pragma unroll
      for (int u = 0; u < 2; ++u) {
        int row = qn * 32 + u * 16 + (lane & 15);
        bh[u] = fragld64(Bch, row, cl);
        bl[u] = fragld64(Bcl, row, cl);
      }
      #pragma unroll
      for (int t = 0; t < 2; ++t)
        #pragma unroll
        for (int u = 0; u < 2; ++u) {
          acc[t][u] = __builtin_amdgcn_mfma_f32_16x16x32_bf16(ah[t], bh[u], acc[t][u], 0, 0, 0);
          acc[t][u] = __builtin_amdgcn_mfma_f32_16x16x32_bf16(ah[t], bl[u], acc[t][u], 0, 0, 0);
          acc[t][u] = __builtin_amdgcn_mfma_f32_16x16x32_bf16(al[t], bh[u], acc[t][u], 0, 0, 0);
        }
    }
    __syncthreads();
  }
  #pragma unroll
  for (int t = 0; t < 2; ++t) {
    int row0 = bi * 64 + qm * 32 + t * 16 + (lane >> 4) * 4;
    #pragma unroll
    for (int u = 0; u < 2; ++u) {
      int col = bj * 64 + qn * 32 + u * 16 + (lane & 15);
      #pragma unroll
      for (int r4 = 0; r4 < 4; ++r4) {
        size_t o = (size_t)(row0 + r4) * CCH + col;
        float v = scale * acc[t][u][r4];
        if (beta != 0.f) v += beta * (b2f(Eh[o]) + b2f(El[o]));
        if (D32) D32[o] = v;
        if (Dh) {
          u16 hh = f2bf(v);
          Dh[o] = hh;
          Dl[o] = f2bf(v - b2f(hh));
        }
        if (Db) Db[o] = f2bf(v);
      }
    }
  }
}

// ================= persistent fused kernel: greduce .. mconst .. apply
struct NSArgs {
  const float* Gp; const float* sums;
  float* cov; float* rowsum; float* snorm; float* coef; float* mconst; float* Zf;
  u16 *Anh, *Anl, *Y1, *Ya, *Z0, *Z1, *Tb, *Zfsh, *Zfsl;
  u16 *Ph, *Pl, *Qh, *Ql, *Zrsh, *Zrsl, *W2h, *W2l, *Mb;
  unsigned* cnt;                       // global barrier counter (zeroed by memset)
  const u16* fcb; const float* X; float* outp;
};

// lean agent-scope grid barrier: arrive (acq_rel) + thread-0 spin (acquire).
// Requires all blocks co-resident: 512 blocks x 64KB LDS = 2/CU x 256 CU (proven
// co-resident by the round-3 cooperative run of this exact shape).
__device__ __forceinline__ void gbar(unsigned* cnt, int nb, int ph) {
  __syncthreads();   // drains all waves' vmem (compiler emits vmcnt(0) before s_barrier)
  if (threadIdx.x == 0) {
    __hip_atomic_fetch_add(cnt, 1u, __ATOMIC_ACQ_REL, __HIP_MEMORY_SCOPE_AGENT);
    unsigned tgt = (unsigned)(ph * nb);
    while (__hip_atomic_load(cnt, __ATOMIC_ACQUIRE, __HIP_MEMORY_SCOPE_AGENT) < tgt)
      __builtin_amdgcn_s_sleep(2);
  }
  __syncthreads();
}

__global__ __launch_bounds__(256, 2) void fused_chain(NSArgs a) {
  __shared__ u16 smem[32768];            // 64 KB, re-purposed per step
  float* redf = (float*)smem;
  int tid = threadIdx.x, bid = blockIdx.x, nb = gridDim.x;
  int ph = 0;

  // ---- step 0: reduce Gram partials -> cov, rowsum(|.|)
  for (int it = 0; it < 4; ++it) {
    int idx = (bid + it * nb) * 256 + tid;
    int b = idx >> 18, ij = idx & (MS - 1);
    int i = ij >> 9, j = ij & 511;
    int pair = ((i >> 7) << 2) | (j >> 7);
    int lij = ((i & 127) << 7) | (j & 127);
    size_t base = ((size_t)(b * 16) * 16 + pair) * 16384 + lij;
    float g = 0.f;
    #pragma unroll
    for (int kc = 0; kc < 16; ++kc) g += a.Gp[base + (size_t)kc * (16 * 16384)];
    const float* s = a.sums + b * CCH;
    float v = (g - s[i] * s[j] * (1.f / (float)NPIX)) * (1.f / (float)(NPIX - 1));
    if (i == j) v += 1e-8f;
    a.cov[idx] = v;
    __syncthreads();
    redf[tid] = fabsf(v);
    __syncthreads();
    for (int st = 128; st > 0; st >>= 1) {
      if (tid < st) redf[tid] += redf[tid + st];
      __syncthreads();
    }
    if (tid == 0) atomicAdd(&a.rowsum[b * CCH + i], redf[0]);
  }
  gbar(a.cnt, nb, ++ph);

  // ---- step 1: norms + An split + Z0 init
  {
    float m = fmaxf(a.rowsum[tid], a.rowsum[tid + 256]);
    redf[tid] = m; __syncthreads();
    for (int s = 128; s > 0; s >>= 1) {
      if (tid < s) redf[tid] = fmaxf(redf[tid], redf[tid + s]);
      __syncthreads();
    }
    float snc = redf[0]; __syncthreads();
    m = fmaxf(a.rowsum[512 + tid], a.rowsum[768 + tid]);
    redf[tid] = m; __syncthreads();
    for (int s = 128; s > 0; s >>= 1) {
      if (tid < s) redf[tid] = fmaxf(redf[tid], redf[tid + s]);
      __syncthreads();
    }
    float sns = redf[0];
    if (bid == 0 && tid == 0) {
      a.snorm[0] = snc; a.snorm[1] = sns;
      a.coef[0] = 0.8f * sqrtf(sns / snc);
    }
    for (int it = 0; it < 4; ++it) {
      int idx = (bid + it * nb) * 256 + tid;
      int b = idx >> 18, ij = idx & (MS - 1);
      int diag = (ij >> 9) == (ij & 511);
      float av = a.cov[idx] * (b ? 1.f / sns : 1.f / snc);
      u16 hi = f2bf(av);
      a.Anh[idx] = hi;
      a.Anl[idx] = f2bf(av - b2f(hi));
      a.Z0[idx] = f2bf((diag ? 3.f - av : -av) * 0.70710678f);
    }
  }
  gbar(a.cnt, nb, ++ph);

  // ---- NS matmul chain (64x64 tiles; tile id t: z = t>>6, bi=(t>>3)&7, bj=t&7)
  #define TILE_IDX int z = t >> 6, r = t & 63, bi = r >> 3, bj = r & 7; (void)z;

  { int t = bid; if (t < 128) { TILE_IDX   // Y1 = An @ Z0^T
      mm_step(a.Anh + (size_t)z * MS, a.Z0 + (size_t)z * MS, a.Y1 + (size_t)z * MS,
              1.f, 0.f, 0, smem, tid, bi, bj); } }
  gbar(a.cnt, nb, ++ph);
  { int t = bid; if (t < 128) { TILE_IDX   // T0 = 3I - Z0 @ Y1^T
      mm_step(a.Z0 + (size_t)z * MS, a.Y1 + (size_t)z * MS, a.Tb + (size_t)z * MS,
              -1.f, 3.f, 0, smem, tid, bi, bj); } }
  gbar(a.cnt, nb, ++ph);
  { int t = bid; if (t < 256) { TILE_IDX   // Ya = Y1@T0/2 ; Z1 = T0@Z0/2
      const u16 *A, *B; u16* D;
      if (z < 2) { A = a.Y1 + (size_t)z * MS; B = a.Tb + (size_t)z * MS; D = a.Ya + (size_t)z * MS; }
      else { A = a.Tb + (size_t)(z - 2) * MS; B = a.Z0 + (size_t)(z - 2) * MS; D = a.Z1 + (size_t)(z - 2) * MS; }
      mm_step(A, B, D, 0.5f, 0.f, 0, smem, tid, bi, bj); } }
  gbar(a.cnt, nb, ++ph);
  { int t = bid; if (t < 128) { TILE_IDX   // T1 = 3I - Z1 @ Ya^T
      mm_step(a.Z1 + (size_t)z * MS, a.Ya + (size_t)z * MS, a.Tb + (size_t)z * MS,
              -1.f, 3.f, 0, smem, tid, bi, bj); } }
  gbar(a.cnt, nb, ++ph);
  { int t = bid; if (t < 256) { TILE_IDX   // Y1 = Ya@T1/2 ; Z0 = T1@Z1/2
      const u16 *A, *B; u16* D;
      if (z < 2) { A = a.Ya + (size_t)z * MS; B = a.Tb + (size_t)z * MS; D = a.Y1 + (size_t)z * MS; }
      else { A = a.Tb + (size_t)(z - 2) * MS; B = a.Z1 + (size_t)(z - 2) * MS; D = a.Z0 + (size_t)(z - 2) * MS; }
      mm_step(A, B, D, 0.5f, 0.f, 0, smem, tid, bi, bj); } }
  gbar(a.cnt, nb, ++ph);
  { int t = bid; if (t < 128) { TILE_IDX   // T2 = 3I - Z0 @ Y1^T
      mm_step(a.Z0 + (size_t)z * MS, a.Y1 + (size_t)z * MS, a.Tb + (size_t)z * MS,
              -1.f, 3.f, 0, smem, tid, bi, bj); } }
  gbar(a.cnt, nb, ++ph);
  { int t = bid; if (t < 128) { TILE_IDX   // Zf = T2 @ Z0 / 2  (fp32)
      mm_step(a.Tb + (size_t)z * MS, a.Z0 + (size_t)z * MS, a.Zf + (size_t)z * MS,
              0.5f, 0.f, 1, smem, tid, bi, bj); } }
  gbar(a.cnt, nb, ++ph);
  // ---- symmetrize + split Zf -> Zfsh/Zfsl
  for (int it = 0; it < 4; ++it) {
    int q = (bid + it * nb) * 256 + tid;
    int b = q >> 18, ij = q & (MS - 1);
    int i = ij >> 9, j = ij & 511;
    size_t base = (size_t)b * MS;
    float v = 0.5f * (a.Zf[base + ij] + a.Zf[base + (size_t)j * CCH + i]);
    u16 hh = f2bf(v);
    a.Zfsh[base + ij] = hh;
    a.Zfsl[base + ij] = f2bf(v - b2f(hh));
  }
  gbar(a.cnt, nb, ++ph);
  { int t = bid; if (t < 256) { TILE_IDX   // P = Zfs@An ; Q = Zfs@Zfs
      const u16 *Ah, *Al, *Bh, *Bl; u16 *Dh, *Dl;
      if (z < 2) { Ah = a.Zfsh + (size_t)z * MS; Al = a.Zfsl + (size_t)z * MS;
                   Bh = a.Anh + (size_t)z * MS;  Bl = a.Anl + (size_t)z * MS;
                   Dh = a.Ph + (size_t)z * MS;   Dl = a.Pl + (size_t)z * MS; }
      else { int zz = z - 2;
             Ah = a.Zfsh + (size_t)zz * MS; Al = a.Zfsl + (size_t)zz * MS;
             Bh = a.Zfsh + (size_t)zz * MS; Bl = a.Zfsl + (size_t)zz * MS;
             Dh = a.Qh + (size_t)zz * MS;   Dl = a.Ql + (size_t)zz * MS; }
      mms_step(Ah, Al, Bh, Bl, (const u16*)0, (const u16*)0, 0.f,
               Dh, Dl, (float*)0, (u16*)0, 1.f, smem, tid, bi, bj); } }
  gbar(a.cnt, nb, ++ph);
  { int t = bid; if (t < 128) { TILE_IDX   // Zr = 1.5 Zfs - 0.5 P@Q  (fp32 -> Zf)
      mms_step(a.Ph + (size_t)z * MS, a.Pl + (size_t)z * MS,
               a.Qh + (size_t)z * MS, a.Ql + (size_t)z * MS,
               a.Zfsh + (size_t)z * MS, a.Zfsl + (size_t)z * MS, 1.5f,
               (u16*)0, (u16*)0, a.Zf + (size_t)z * MS, (u16*)0,
               -0.5f, smem, tid, bi, bj); } }
  gbar(a.cnt, nb, ++ph);
  // ---- symmetrize + split Zr -> Zrsh/Zrsl
  for (int it = 0; it < 4; ++it) {
    int q = (bid + it * nb) * 256 + tid;
    int b = q >> 18, ij = q & (MS - 1);
    int i = ij >> 9, j = ij & 511;
    size_t base = (size_t)b * MS;
    float v = 0.5f * (a.Zf[base + ij] + a.Zf[base + (size_t)j * CCH + i]);
    u16 hh = f2bf(v);
    a.Zrsh[base + ij] = hh;
    a.Zrsl[base + ij] = f2bf(v - b2f(hh));
  }
  gbar(a.cnt, nb, ++ph);
  { int t = bid; if (t < 64) { TILE_IDX    // W2 = An_s @ Zrs_s (split out)
      mms_step(a.Anh + MS, a.Anl + MS, a.Zrsh + MS, a.Zrsl + MS,
               (const u16*)0, (const u16*)0, 0.f,
               a.W2h, a.W2l, (float*)0, (u16*)0, 1.f, smem, tid, bi, bj); } }
  gbar(a.cnt, nb, ++ph);
  { int t = bid; if (t < 64) { TILE_IDX    // M = coef * W2 @ Zrs_c (bf16)
      float sc = a.coef[0];
      mms_step(a.W2h, a.W2l, a.Zrsh, a.Zrsl,
               (const u16*)0, (const u16*)0, 0.f,
               (u16*)0, (u16*)0, (float*)0, a.Mb, sc, smem, tid, bi, bj); } }
  gbar(a.cnt, nb, ++ph);
  // ---- mconst[c] = (0.8*ssum[c] - (M @ csum)[c]) / N
  if (bid < 64) {
    int c = bid * 8 + (tid >> 5);
    int l = tid & 31;
    float s = 0.f;
    #pragma unroll
    for (int k = 0; k < 16; ++k) {
      int j = l + 32 * k;
      s += b2f(a.Mb[(size_t)c * CCH + j]) * a.sums[j];
    }
    s += __shfl_down(s, 16, 32);
    s += __shfl_down(s, 8, 32);
    s += __shfl_down(s, 4, 32);
    s += __shfl_down(s, 2, 32);
    s += __shfl_down(s, 1, 32);
    if (l == 0) a.mconst[c] = (0.8f * a.sums[512 + c] - s) * (1.f / (float)NPIX);
  }
  gbar(a.cnt, nb, ++ph);

  // ---- apply: out = fcb @ M^T + mconst + 0.2 X   (128-tiles, Kt=64 dbuf)
  {
    int bi = bid >> 2;    // n tile (0..127)
    int bj = bid & 3;     // c tile (0..3)
    int w = tid >> 6, lane = tid & 63;
    int qm = w & 1, qn = w >> 1;
    const u16* ssrc = (w < 2) ? a.fcb + (size_t)(bi * 128) * CCH
                              : a.Mb + (size_t)(bj * 128) * CCH;
    int rbase = (w & 1) * 64;
    // LDS: A buf c at smem + c*8192; B buf c at smem + 16384 + c*8192 (u16 offs)
    f32x4 acc[4][4];
    #pragma unroll
    for (int t = 0; t < 4; ++t)
      #pragma unroll
      for (int u = 0; u < 4; ++u) acc[t][u] = (f32x4)(0.f);

    #pragma unroll
    for (int i = 0; i < 8; ++i)
      stage8_64(ssrc, CCH, rbase + i * 8, 0, (w < 2) ? smem : smem + 16384, lane);
    __syncthreads();

    for (int st = 0; st < 8; ++st) {
      int cur = st & 1;
      if (st < 7) {
        u16* sdst = ((w < 2) ? smem : smem + 16384) + (cur ^ 1) * 8192;
        #pragma unroll
        for (int i = 0; i < 8; ++i)
          stage8_64(ssrc, CCH, rbase + i * 8, (st + 1) * 64, sdst, lane);
      }
      u16* Ac = smem + cur * 8192;
      u16* Bc = smem + 16384 + cur * 8192;
      #pragma unroll
      for (int s = 0; s < 2; ++s) {
        int cl = s * 4 + (lane >> 4);
        bf16x8 av[4], bb[4];
        #pragma unroll
        for (int t = 0; t < 4; ++t) av[t] = fragld64(Ac, qm * 64 + t * 16 + (lane & 15), cl);
        #pragma unroll
        for (int u = 0; u < 4; ++u) bb[u] = fragld64(Bc, qn * 64 + u * 16 + (lane & 15), cl);
        #pragma unroll
        for (int t = 0; t < 4; ++t)
          #pragma unroll
          for (int u = 0; u < 4; ++u)
            acc[t][u] = __builtin_amdgcn_mfma_f32_16x16x32_bf16(av[t], bb[u], acc[t][u], 0, 0, 0);
      }
      __syncthreads();
    }
    #pragma unroll
    for (int t = 0; t < 4; ++t) {
      int row0 = bi * 128 + qm * 64 + t * 16 + (lane >> 4) * 4;
      #pragma unroll
      for (int u = 0; u < 4; ++u) {
        int col = bj * 128 + qn * 64 + u * 16 + (lane & 15);
        float cst = a.mconst[col];
        #pragma unroll
        for (int r4 = 0; r4 < 4; ++r4) {
          size_t o = (size_t)(row0 + r4) * CCH + col;
          a.outp[o] = acc[t][u][r4] + cst + 0.2f * a.X[o];
        }
      }
    }
  }
  #undef TILE_IDX
}

// ================================================================ launcher
extern "C" void kernel_launch(void* const* d_in, const int* in_sizes, int n_in,
                              void* d_out, int out_size, void* d_ws, size_t ws_size,
                              hipStream_t stream) {
  const float* Xc = (const float*)d_in[0];
  const float* Xs = (const float*)d_in[1];
  float* out = (float*)d_out;

  float* f = (float*)d_ws;
  float* sums   = f;                     // 1024
  float* rowsum = f + 1024;              // 1024
  unsigned* cnt = (unsigned*)(f + 2048); // barrier counter (zeroed each launch)
  float* cov    = f + 2048 + 2 * MS;     // 2*MS
  float* snorm  = cov + 2 * MS;          // 8
  float* coef   = snorm + 8;             // 8
  float* mconst = coef + 8;              // 512
  float* Zf     = mconst + 512;          // 2*MS (fp32, reused for Zr)

  // Gram split-K partials live in d_out (dead before apply phase): 32 MiB exactly.
  float* Gp = (float*)d_out;

  u16* h   = (u16*)(Zf + 2 * MS);
  u16* fct = h;                          // 2*512*16384 u16 (dead after gram)
  u16* fcb = h + (size_t)2 * CCH * NPIX; // 16384*512 u16
  const size_t B2 = 2 * MS;
  u16* Anh  = fct + 0 * B2;
  u16* Anl  = fct + 1 * B2;
  u16* Y1   = fct + 2 * B2;
  u16* Ya   = fct + 3 * B2;
  u16* Z0   = fct + 4 * B2;
  u16* Z1   = fct + 5 * B2;
  u16* Tb   = fct + 6 * B2;
  u16* Zfsh = fct + 7 * B2;
  u16* Zfsl = fct + 8 * B2;
  u16* Ph   = fct + 9 * B2;
  u16* Pl   = fct + 10 * B2;
  u16* Qh   = fct + 11 * B2;
  u16* Ql   = fct + 12 * B2;
  u16* Zrsh = fct + 13 * B2;
  u16* Zrsl = fct + 14 * B2;
  u16* W2h  = fct + 15 * B2;
  u16* W2l  = W2h + MS;
  u16* Mb   = W2l + MS;

  // zero: sums + rowsum + barrier counter (graph replay resets it each run)
  hipMemsetAsync(d_ws, 0, 2064 * sizeof(float), stream);

  prep_k<<<dim3(256, 8, 2), 256, 0, stream>>>(Xc, Xs, sums, fct, fcb);
  gram_part<<<dim3(16, 16, 2), 256, 0, stream>>>(fct, Gp);

  NSArgs a;
  a.Gp = Gp; a.sums = sums; a.cov = cov; a.rowsum = rowsum;
  a.snorm = snorm; a.coef = coef; a.mconst = mconst; a.Zf = Zf;
  a.Anh = Anh; a.Anl = Anl; a.Y1 = Y1; a.Ya = Ya; a.Z0 = Z0; a.Z1 = Z1; a.Tb = Tb;
  a.Zfsh = Zfsh; a.Zfsl = Zfsl; a.Ph = Ph; a.Pl = Pl; a.Qh = Qh; a.Ql = Ql;
  a.Zrsh = Zrsh; a.Zrsl = Zrsl; a.W2h = W2h; a.W2l = W2l; a.Mb = Mb;
  a.cnt = cnt; a.fcb = fcb; a.X = Xc; a.outp = out;
  fused_chain<<<dim3(512), dim3(256), 0, stream>>>(a);
}

// Round 5
// 290.203 us; speedup vs baseline: 4.5876x; 4.5876x over previous
//
#include <hip/hip_runtime.h>
#include <math.h>

#define NPIX 16384      // H*W
#define CCH  512        // channels
#define MS   262144     // 512*512

typedef unsigned short u16;
typedef unsigned int u32;
typedef __attribute__((ext_vector_type(8))) short bf16x8;   // 8 bf16 = 4 VGPR
typedef __attribute__((ext_vector_type(4))) float f32x4;

__device__ __forceinline__ u16 f2bf(float f) {
  u32 u = __builtin_bit_cast(u32, f);
  u += 0x7fffu + ((u >> 16) & 1u);    // round-to-nearest-even
  return (u16)(u >> 16);
}
__device__ __forceinline__ float b2f(u16 h) {
  u32 u = ((u32)h) << 16;
  return __builtin_bit_cast(float, u);
}

typedef const __attribute__((address_space(1))) u32* gp_t;
typedef __attribute__((address_space(3))) u32* lp_t;
__device__ __forceinline__ void gl_lds16(const void* g, void* l) {
  __builtin_amdgcn_global_load_lds((gp_t)g, (lp_t)l, 16, 0, 0);
}

// ---- Kt=128 staged tile, XOR chunk swizzle (LDS row = 128 bf16 = 16x16B chunks)
__device__ __forceinline__ void stage4(const u16* tile, size_t stride, int rl,
                                       int k0, u16* lds, int lane) {
  int lr = lane >> 4;                               // 4 rows per instruction
  int cg2 = (lane & 15) ^ ((rl + lr) & 15);         // swizzled global chunk
  gl_lds16(tile + (size_t)(rl + lr) * stride + k0 + cg2 * 8,
           lds + (size_t)rl * 128);
}
__device__ __forceinline__ bf16x8 fragld(const u16* lds, int row, int cl) {
  return *(const bf16x8*)&lds[(size_t)row * 128 + (size_t)((cl ^ (row & 15)) << 3)];
}

// ---- Kt=64 variants (LDS row = 64 bf16 = 8x16B chunks); 8 rows per gl_lds16
__device__ __forceinline__ void stage8_64(const u16* tile, size_t stride, int rl,
                                          int k0, u16* lds, int lane) {
  int lr = lane >> 3;                               // 8 rows per instruction
  int cg2 = (lane & 7) ^ ((rl + lr) & 7);           // swizzled global chunk
  gl_lds16(tile + (size_t)(rl + lr) * stride + k0 + cg2 * 8,
           lds + (size_t)rl * 64);
}
__device__ __forceinline__ bf16x8 fragld64(const u16* lds, int row, int cl) {
  return *(const bf16x8*)&lds[(size_t)row * 64 + (size_t)((cl ^ (row & 7)) << 3)];
}

// ================= prep: one pass over X -> colsums, fct (bf16 [c][n]), fcb (bf16 [n][c])
__global__ __launch_bounds__(256) void prep_k(const float* __restrict__ Xc,
                                              const float* __restrict__ Xs,
                                              float* __restrict__ sums,
                                              u16* __restrict__ fct,
                                              u16* __restrict__ fcb) {
  int b = blockIdx.z;
  const float* X = b ? Xs : Xc;
  u16* outT = fct + (size_t)b * ((size_t)CCH * NPIX);
  __shared__ float T[64][65];
  __shared__ float red2[64][4];
  int n0 = blockIdx.x * 64, c0 = blockIdx.y * 64;
  int t = threadIdx.x;
  int cr = t & 15, nr = t >> 4;
  #pragma unroll
  for (int rr = 0; rr < 4; ++rr) {
    int n = nr + rr * 16;
    float4 v = *(const float4*)&X[(size_t)(n0 + n) * CCH + c0 + cr * 4];
    T[n][cr * 4 + 0] = v.x;
    T[n][cr * 4 + 1] = v.y;
    T[n][cr * 4 + 2] = v.z;
    T[n][cr * 4 + 3] = v.w;
    if (b == 0) {
      ushort4 q;
      q.x = f2bf(v.x); q.y = f2bf(v.y); q.z = f2bf(v.z); q.w = f2bf(v.w);
      *(ushort4*)&fcb[(size_t)(n0 + n) * CCH + c0 + cr * 4] = q;
    }
  }
  __syncthreads();
  int cl = t >> 2, np = (t & 3) * 16;
  size_t obase = (size_t)(c0 + cl) * NPIX + n0 + np;
  float s = 0.f;
  #pragma unroll
  for (int i = 0; i < 16; i += 4) {
    float v0 = T[np + i + 0][cl], v1 = T[np + i + 1][cl];
    float v2 = T[np + i + 2][cl], v3 = T[np + i + 3][cl];
    s += v0 + v1 + v2 + v3;
    ushort4 o;
    o.x = f2bf(v0); o.y = f2bf(v1); o.z = f2bf(v2); o.w = f2bf(v3);
    *(ushort4*)&outT[obase + i] = o;
  }
  red2[cl][t & 3] = s;
  __syncthreads();
  if (t < 64) {
    float cs = red2[t][0] + red2[t][1] + red2[t][2] + red2[t][3];
    atomicAdd(&sums[b * CCH + c0 + t], cs);
  }
}

// ================= Gram partials, upper triangle only (G symmetric):
// 10 pairs x 16 kc x 2 batches = 320 blocks, all co-resident at 2/CU.
// K=1024 per block; 2-phase dbuf staging; plain stores to Gp (tile-local).
__global__ __launch_bounds__(256, 2) void gram_part(const u16* __restrict__ fct,
                                                    float* __restrict__ Gp) {
  int kc = blockIdx.x;               // 0..15, K chunk of 1024
  int pair = blockIdx.y;             // 0..9  (upper-triangle pair index)
  int b = blockIdx.z;
  int bi = (pair < 4) ? 0 : (pair < 7) ? 1 : (pair < 9) ? 2 : 3;
  int bj = (pair < 4) ? pair : (pair < 7) ? pair - 3 : (pair < 9) ? pair - 5 : 3;
  const u16* Xb = fct + (size_t)b * ((size_t)CCH * NPIX);
  __shared__ u16 As[2][128 * 64];    // 2 x 16 KB
  __shared__ u16 Bs[2][128 * 64];    // 2 x 16 KB
  int tid = threadIdx.x, w = tid >> 6, lane = tid & 63;
  int qm = w & 1, qn = w >> 1;
  const u16* ssrc = (w < 2) ? Xb + (size_t)(bi * 128) * NPIX
                            : Xb + (size_t)(bj * 128) * NPIX;
  int rbase = (w & 1) * 64;
  f32x4 acc[4][4];
  #pragma unroll
  for (int t = 0; t < 4; ++t)
    #pragma unroll
    for (int u = 0; u < 4; ++u) acc[t][u] = (f32x4)(0.f);

  // prologue: stage st=0 into buf 0
  #pragma unroll
  for (int i = 0; i < 8; ++i)
    stage8_64(ssrc, NPIX, rbase + i * 8, kc * 1024, (w < 2) ? As[0] : Bs[0], lane);
  __syncthreads();

  for (int st = 0; st < 16; ++st) {
    int cur = st & 1;
    if (st < 15) {
      int k0n = kc * 1024 + (st + 1) * 64;
      #pragma unroll
      for (int i = 0; i < 8; ++i)
        stage8_64(ssrc, NPIX, rbase + i * 8, k0n,
                  (w < 2) ? As[cur ^ 1] : Bs[cur ^ 1], lane);
    }
    #pragma unroll
    for (int s = 0; s < 2; ++s) {
      int cl = s * 4 + (lane >> 4);
      bf16x8 a[4], bb[4];
      #pragma unroll
      for (int t = 0; t < 4; ++t) a[t] = fragld64(As[cur], qm * 64 + t * 16 + (lane & 15), cl);
      #pragma unroll
      for (int u = 0; u < 4; ++u) bb[u] = fragld64(Bs[cur], qn * 64 + u * 16 + (lane & 15), cl);
      #pragma unroll
      for (int t = 0; t < 4; ++t)
        #pragma unroll
        for (int u = 0; u < 4; ++u)
          acc[t][u] = __builtin_amdgcn_mfma_f32_16x16x32_bf16(a[t], bb[u], acc[t][u], 0, 0, 0);
    }
    __syncthreads();
  }
  // plain stores, tile-local layout: Gp[(b*16+kc)*10 + pair][128][128]
  size_t tbase = ((size_t)(b * 16 + kc) * 10 + pair) * 16384;
  #pragma unroll
  for (int t = 0; t < 4; ++t) {
    int row0 = qm * 64 + t * 16 + (lane >> 4) * 4;
    #pragma unroll
    for (int u = 0; u < 4; ++u) {
      int col = qn * 64 + u * 16 + (lane & 15);
      #pragma unroll
      for (int r4 = 0; r4 < 4; ++r4)
        Gp[tbase + (size_t)(row0 + r4) * 128 + col] = acc[t][u][r4];
    }
  }
}

// ================= reduce partials (mirror-read lower triangle; bit-identical)
// + cov = (G - s s^T/N)/(N-1) + eps I ; rowsum |.| atomics
__global__ __launch_bounds__(256) void gram_reduce(const float* __restrict__ Gp,
                                                   const float* __restrict__ sums,
                                                   float* __restrict__ cov,
                                                   float* __restrict__ rowsum) {
  int idx = blockIdx.x * 256 + threadIdx.x;   // 0 .. 2*MS-1
  int b = idx >> 18;
  int ij = idx & (MS - 1);
  int i = ij >> 9, j = ij & 511;
  int ti = i >> 7, tj = j >> 7;
  int p, lij;
  if (ti <= tj) {
    p = ti * 4 - ((ti * (ti + 1)) >> 1) + tj;
    lij = ((i & 127) << 7) | (j & 127);
  } else {
    p = tj * 4 - ((tj * (tj + 1)) >> 1) + ti;
    lij = ((j & 127) << 7) | (i & 127);       // transposed read: G(i,j)=G(j,i) bitwise
  }
  size_t base = ((size_t)(b * 16) * 10 + p) * 16384 + lij;
  float g = 0.f;
  #pragma unroll
  for (int kc = 0; kc < 16; ++kc)
    g += Gp[base + (size_t)kc * (10 * 16384)];
  const float* s = sums + b * CCH;
  float v = (g - s[i] * s[j] * (1.f / (float)NPIX)) * (1.f / (float)(NPIX - 1));
  if (i == j) v += 1e-8f;
  cov[idx] = v;
  __shared__ float red[256];
  int t = threadIdx.x;
  red[t] = fabsf(v);
  __syncthreads();
  for (int st = 128; st > 0; st >>= 1) {
    if (t < st) red[t] += red[t + st];
    __syncthreads();
  }
  if (t == 0) atomicAdd(&rowsum[b * CCH + i], red[0]);
}

// ================= NS init (+ fused norm/coef): An split; Z0 = (c/2)(3I-Â), c^2=2
__global__ __launch_bounds__(256) void nsinit_k(const float* __restrict__ cov,
                                                const float* __restrict__ rowsum,
                                                float* __restrict__ snorm,
                                                float* __restrict__ coef,
                                                u16* __restrict__ Anh,
                                                u16* __restrict__ Anl,
                                                u16* __restrict__ Z0) {
  __shared__ float red[256];
  int tid = threadIdx.x, blk = blockIdx.x;
  float m = fmaxf(rowsum[tid], rowsum[tid + 256]);
  red[tid] = m; __syncthreads();
  for (int s = 128; s > 0; s >>= 1) {
    if (tid < s) red[tid] = fmaxf(red[tid], red[tid + s]);
    __syncthreads();
  }
  float snc = red[0]; __syncthreads();
  m = fmaxf(rowsum[512 + tid], rowsum[768 + tid]);
  red[tid] = m; __syncthreads();
  for (int s = 128; s > 0; s >>= 1) {
    if (tid < s) red[tid] = fmaxf(red[tid], red[tid + s]);
    __syncthreads();
  }
  float sns = red[0];
  if (blk == 0 && tid == 0) {
    snorm[0] = snc; snorm[1] = sns;
    coef[0] = 0.8f * sqrtf(sns / snc);
  }
  int idx = blk * 256 + tid;                 // 0 .. 2*MS-1 (grid 2048)
  int b = idx >> 18;
  int ij = idx & (MS - 1);
  int diag = (ij >> 9) == (ij & 511);
  float av = cov[idx] * (b ? 1.f / sns : 1.f / snc);
  u16 hi = f2bf(av);
  Anh[idx] = hi;
  Anl[idx] = f2bf(av - b2f(hi));
  float t0 = (diag ? 3.f - av : -av) * 0.70710678f;   // boosted first step
  Z0[idx] = f2bf(t0);
}

// ================= plain bf16 NS matmul, 64x64 tiles, Kt=128 dbuf: D = diag*I + scale*(A @ B^T)
struct MM16 {
  const u16* A[4];
  const u16* B[4];
  void* D[4];
  float scale, diag;
  int outFp32;
};

__global__ __launch_bounds__(256) void mm16_k(MM16 args) {
  int z = blockIdx.z;
  const u16* __restrict__ A = args.A[z];
  const u16* __restrict__ B = args.B[z];
  int bi = blockIdx.y, bj = blockIdx.x;
  __shared__ u16 As[2][64 * 128];    // 2 x 16 KB
  __shared__ u16 Bs[2][64 * 128];    // 2 x 16 KB
  int tid = threadIdx.x, w = tid >> 6, lane = tid & 63;
  int qm = w & 1, qn = w >> 1;
  const u16* ssrc = ((w < 2) ? A + (size_t)(bi * 64) * CCH : B + (size_t)(bj * 64) * CCH);
  int rbase = (w & 1) * 32;
  f32x4 acc[2][2];
  #pragma unroll
  for (int t = 0; t < 2; ++t)
    #pragma unroll
    for (int u = 0; u < 2; ++u) acc[t][u] = (f32x4)(0.f);

  // prologue: stage st=0 into buf 0
  #pragma unroll
  for (int i = 0; i < 8; ++i)
    stage4(ssrc, CCH, rbase + i * 4, 0, (w < 2) ? As[0] : Bs[0], lane);
  __syncthreads();

  for (int st = 0; st < 4; ++st) {
    int cur = st & 1;
    if (st < 3) {
      #pragma unroll
      for (int i = 0; i < 8; ++i)
        stage4(ssrc, CCH, rbase + i * 4, (st + 1) * 128,
               (w < 2) ? As[cur ^ 1] : Bs[cur ^ 1], lane);
    }
    #pragma unroll
    for (int s = 0; s < 4; ++s) {
      int cl = s * 4 + (lane >> 4);
      bf16x8 a[2], bb[2];
      #pragma unroll
      for (int t = 0; t < 2; ++t) a[t] = fragld(As[cur], qm * 32 + t * 16 + (lane & 15), cl);
      #pragma unroll
      for (int u = 0; u < 2; ++u) bb[u] = fragld(Bs[cur], qn * 32 + u * 16 + (lane & 15), cl);
      #pragma unroll
      for (int t = 0; t < 2; ++t)
        #pragma unroll
        for (int u = 0; u < 2; ++u)
          acc[t][u] = __builtin_amdgcn_mfma_f32_16x16x32_bf16(a[t], bb[u], acc[t][u], 0, 0, 0);
    }
    __syncthreads();
  }
  float sc = args.scale;
  #pragma unroll
  for (int t = 0; t < 2; ++t) {
    int row0 = bi * 64 + qm * 32 + t * 16 + (lane >> 4) * 4;
    #pragma unroll
    for (int u = 0; u < 2; ++u) {
      int col = bj * 64 + qn * 32 + u * 16 + (lane & 15);
      #pragma unroll
      for (int r4 = 0; r4 < 4; ++r4) {
        float v = sc * acc[t][u][r4];
        if (row0 + r4 == col) v += args.diag;
        size_t o = (size_t)(row0 + r4) * CCH + col;
        if (args.outFp32) ((float*)args.D[z])[o] = v;
        else ((u16*)args.D[z])[o] = f2bf(v);
      }
    }
  }
}

// ================= symmetrize + split fp32 -> hi/lo bf16
__global__ __launch_bounds__(256) void symsplit_k(const float* __restrict__ src,
                                                  u16* __restrict__ hi,
                                                  u16* __restrict__ lo) {
  int b = blockIdx.y;
  int ij = blockIdx.x * 256 + threadIdx.x;   // 0..MS-1
  int i = ij >> 9, j = ij & 511;
  size_t base = (size_t)b * MS;
  float v = 0.5f * (src[base + ij] + src[base + (size_t)j * CCH + i]);
  u16 h = f2bf(v);
  hi[base + ij] = h;
  lo[base + ij] = f2bf(v - b2f(h));
}

// ================= split-bf16 matmul (~fp32 quality), 64x64 tiles, Kt=64 dbuf
struct MMS {
  const u16 *Ah[4], *Al[4], *Bh[4], *Bl[4];
  const u16 *Eh[4], *El[4];
  u16 *Dh[4], *Dl[4];
  float *D32[4];
  u16 *Db[4];
  float scale, beta;
  const float* coefPtr;
};

__global__ __launch_bounds__(256) void mmsplit_k(MMS args) {
  int z = blockIdx.z;
  int bi = blockIdx.y, bj = blockIdx.x;
  __shared__ u16 Ash[2][64 * 64], Asl[2][64 * 64];   // 4 x 8 KB
  __shared__ u16 Bsh[2][64 * 64], Bsl[2][64 * 64];   // 4 x 8 KB
  int tid = threadIdx.x, w = tid >> 6, lane = tid & 63;
  int qm = w & 1, qn = w >> 1;
  const u16* sp = (w == 0) ? args.Ah[z] : (w == 1) ? args.Al[z]
                : (w == 2) ? args.Bh[z] : args.Bl[z];
  const u16* ssrc = sp + (size_t)(((w < 2) ? bi : bj) * 64) * CCH;
  u16* sd0 = (w == 0) ? Ash[0] : (w == 1) ? Asl[0] : (w == 2) ? Bsh[0] : Bsl[0];
  u16* sd1 = (w == 0) ? Ash[1] : (w == 1) ? Asl[1] : (w == 2) ? Bsh[1] : Bsl[1];
  f32x4 acc[2][2];
  #pragma unroll
  for (int t = 0; t < 2; ++t)
    #pragma unroll
    for (int u = 0; u < 2; ++u) acc[t][u] = (f32x4)(0.f);

  // prologue: stage st=0 into buf 0
  #pragma unroll
  for (int i = 0; i < 8; ++i)
    stage8_64(ssrc, CCH, i * 8, 0, sd0, lane);
  __syncthreads();

  for (int st = 0; st < 8; ++st) {
    int cur = st & 1;
    if (st < 7) {
      u16* sdn = cur ? sd0 : sd1;
      #pragma unroll
      for (int i = 0; i < 8; ++i)
        stage8_64(ssrc, CCH, i * 8, (st + 1) * 64, sdn, lane);
    }
    #pragma unroll
    for (int s = 0; s < 2; ++s) {
      int cl = s * 4 + (lane >> 4);
      bf16x8 ah[2], al[2], bh[2], bl[2];
      #pragma unroll
      for (int t = 0; t < 2; ++t) {
        int row = qm * 32 + t * 16 + (lane & 15);
        ah[t] = fragld64(Ash[cur], row, cl);
        al[t] = fragld64(Asl[cur], row, cl);
      }
      #pragma unroll
      for (int u = 0; u < 2; ++u) {
        int row = qn * 32 + u * 16 + (lane & 15);
        bh[u] = fragld64(Bsh[cur], row, cl);
        bl[u] = fragld64(Bsl[cur], row, cl);
      }
      #pragma unroll
      for (int t = 0; t < 2; ++t)
        #pragma unroll
        for (int u = 0; u < 2; ++u) {
          acc[t][u] = __builtin_amdgcn_mfma_f32_16x16x32_bf16(ah[t], bh[u], acc[t][u], 0, 0, 0);
          acc[t][u] = __builtin_amdgcn_mfma_f32_16x16x32_bf16(ah[t], bl[u], acc[t][u], 0, 0, 0);
          acc[t][u] = __builtin_amdgcn_mfma_f32_16x16x32_bf16(al[t], bh[u], acc[t][u], 0, 0, 0);
        }
    }
    __syncthreads();
  }
  float sc = args.scale;
  if (args.coefPtr) sc *= *args.coefPtr;
  #pragma unroll
  for (int t = 0; t < 2; ++t) {
    int row0 = bi * 64 + qm * 32 + t * 16 + (lane >> 4) * 4;
    #pragma unroll
    for (int u = 0; u < 2; ++u) {
      int col = bj * 64 + qn * 32 + u * 16 + (lane & 15);
      #pragma unroll
      for (int r4 = 0; r4 < 4; ++r4) {
        size_t o = (size_t)(row0 + r4) * CCH + col;
        float v = sc * acc[t][u][r4];
        if (args.beta != 0.f) v += args.beta * (b2f(args.Eh[z][o]) + b2f(args.El[z][o]));
        if (args.D32[z]) args.D32[z][o] = v;
        if (args.Dh[z]) {
          u16 h = f2bf(v);
          args.Dh[z][o] = h;
          args.Dl[z][o] = f2bf(v - b2f(h));
        }
        if (args.Db[z]) args.Db[z][o] = f2bf(v);
      }
    }
  }
}

// ================= mconst[c] = (0.8*ssum[c] - (M @ csum)[c]) / N
__global__ __launch_bounds__(256) void mconst_k(const u16* __restrict__ Mb,
                                                const float* __restrict__ sums,
                                                float* __restrict__ mconst) {
  int c = blockIdx.x * 8 + (threadIdx.x >> 5);   // grid 64
  int l = threadIdx.x & 31;
  float s = 0.f;
  #pragma unroll
  for (int k = 0; k < 16; ++k) {
    int j = l + 32 * k;
    s += b2f(Mb[(size_t)c * CCH + j]) * sums[j];
  }
  s += __shfl_down(s, 16, 32);
  s += __shfl_down(s, 8, 32);
  s += __shfl_down(s, 4, 32);
  s += __shfl_down(s, 2, 32);
  s += __shfl_down(s, 1, 32);
  if (l == 0) mconst[c] = (0.8f * sums[512 + c] - s) * (1.f / (float)NPIX);
}

// ================= apply: out = fcb @ M^T + mconst + 0.2 X   (128-tiles, Kt=64 dbuf)
__global__ __launch_bounds__(256) void apply_mfma(const u16* __restrict__ fcb,
                                                  const u16* __restrict__ Mb,
                                                  const float* __restrict__ mconst,
                                                  const float* __restrict__ X,
                                                  float* __restrict__ out) {
  int bi = blockIdx.y;    // n tile (0..127)
  int bj = blockIdx.x;    // c tile (0..3)
  __shared__ u16 As[2][128 * 64];    // 2 x 16 KB
  __shared__ u16 Bs[2][128 * 64];    // 2 x 16 KB
  int tid = threadIdx.x, w = tid >> 6, lane = tid & 63;
  int qm = w & 1, qn = w >> 1;
  const u16* ssrc = (w < 2) ? fcb + (size_t)(bi * 128) * CCH
                            : Mb + (size_t)(bj * 128) * CCH;
  int rbase = (w & 1) * 64;
  f32x4 acc[4][4];
  #pragma unroll
  for (int t = 0; t < 4; ++t)
    #pragma unroll
    for (int u = 0; u < 4; ++u) acc[t][u] = (f32x4)(0.f);

  // prologue: stage st=0 into buf 0
  #pragma unroll
  for (int i = 0; i < 8; ++i)
    stage8_64(ssrc, CCH, rbase + i * 8, 0, (w < 2) ? As[0] : Bs[0], lane);
  __syncthreads();

  for (int st = 0; st < 8; ++st) {
    int cur = st & 1;
    if (st < 7) {
      #pragma unroll
      for (int i = 0; i < 8; ++i)
        stage8_64(ssrc, CCH, rbase + i * 8, (st + 1) * 64,
                  (w < 2) ? As[cur ^ 1] : Bs[cur ^ 1], lane);
    }
    #pragma unroll
    for (int s = 0; s < 2; ++s) {
      int cl = s * 4 + (lane >> 4);
      bf16x8 a[4], bb[4];
      #pragma unroll
      for (int t = 0; t < 4; ++t) a[t] = fragld64(As[cur], qm * 64 + t * 16 + (lane & 15), cl);
      #pragma unroll
      for (int u = 0; u < 4; ++u) bb[u] = fragld64(Bs[cur], qn * 64 + u * 16 + (lane & 15), cl);
      #pragma unroll
      for (int t = 0; t < 4; ++t)
        #pragma unroll
        for (int u = 0; u < 4; ++u)
          acc[t][u] = __builtin_amdgcn_mfma_f32_16x16x32_bf16(a[t], bb[u], acc[t][u], 0, 0, 0);
    }
    __syncthreads();
  }
  #pragma unroll
  for (int t = 0; t < 4; ++t) {
    int row0 = bi * 128 + qm * 64 + t * 16 + (lane >> 4) * 4;
    #pragma unroll
    for (int u = 0; u < 4; ++u) {
      int col = bj * 128 + qn * 64 + u * 16 + (lane & 15);
      float cst = mconst[col];
      #pragma unroll
      for (int r4 = 0; r4 < 4; ++r4) {
        size_t o = (size_t)(row0 + r4) * CCH + col;
        out[o] = acc[t][u][r4] + cst + 0.2f * X[o];
      }
    }
  }
}

// ================================================================ launcher
extern "C" void kernel_launch(void* const* d_in, const int* in_sizes, int n_in,
                              void* d_out, int out_size, void* d_ws, size_t ws_size,
                              hipStream_t stream) {
  const float* Xc = (const float*)d_in[0];
  const float* Xs = (const float*)d_in[1];
  float* out = (float*)d_out;

  float* f = (float*)d_ws;
  float* sums   = f;                     // 1024
  float* rowsum = f + 1024;              // 1024
  // f+2048 .. f+2048+2*MS: former G region (unused; kept to preserve layout)
  float* cov    = f + 2048 + 2 * MS;     // 2*MS
  float* snorm  = cov + 2 * MS;          // 8
  float* coef   = snorm + 8;             // 8
  float* mconst = coef + 8;              // 512
  float* Zf     = mconst + 512;          // 2*MS (fp32, reused for Zr)

  // Gram split-K partials live in d_out (dead until apply_mfma):
  // 2 batches x 16 kc x 10 triangle pairs x 128x128 fp32 = 20 MiB < 32 MiB out.
  float* Gp = (float*)d_out;

  u16* h   = (u16*)(Zf + 2 * MS);
  u16* fct = h;                          // 2*512*16384 u16 (dead after gram)
  u16* fcb = h + (size_t)2 * CCH * NPIX; // 16384*512 u16
  const size_t B2 = 2 * MS;
  u16* Anh  = fct + 0 * B2;
  u16* Anl  = fct + 1 * B2;
  u16* Y1   = fct + 2 * B2;
  u16* Ya   = fct + 3 * B2;
  u16* Z0   = fct + 4 * B2;
  u16* Z1   = fct + 5 * B2;
  u16* Tb   = fct + 6 * B2;
  u16* Zfsh = fct + 7 * B2;
  u16* Zfsl = fct + 8 * B2;
  u16* Ph   = fct + 9 * B2;
  u16* Pl   = fct + 10 * B2;
  u16* Qh   = fct + 11 * B2;
  u16* Ql   = fct + 12 * B2;
  u16* Zrsh = fct + 13 * B2;
  u16* Zrsl = fct + 14 * B2;
  u16* W2h  = fct + 15 * B2;
  u16* W2l  = W2h + MS;
  u16* Mb   = W2l + MS;

  // zero: sums + rowsum only
  hipMemsetAsync(d_ws, 0, 2048 * sizeof(float), stream);

  prep_k<<<dim3(256, 8, 2), 256, 0, stream>>>(Xc, Xs, sums, fct, fcb);
  gram_part<<<dim3(16, 10, 2), 256, 0, stream>>>(fct, Gp);
  gram_reduce<<<2048, 256, 0, stream>>>(Gp, sums, cov, rowsum);
  nsinit_k<<<2048, 256, 0, stream>>>(cov, rowsum, snorm, coef, Anh, Anl, Z0);

  // NS: boosted first step (in nsinit) + 2 full iterations + final Z-update
  {
    MM16 y1{};
    y1.A[0] = Anh;      y1.B[0] = Z0;      y1.D[0] = Y1;
    y1.A[1] = Anh + MS; y1.B[1] = Z0 + MS; y1.D[1] = Y1 + MS;
    y1.scale = 1.f; y1.diag = 0.f; y1.outFp32 = 0;
    mm16_k<<<dim3(8, 8, 2), 256, 0, stream>>>(y1);
  }
  {
    MM16 t{};   // T0 = 3I - Z0 @ Y1
    t.A[0] = Z0;      t.B[0] = Y1;      t.D[0] = Tb;
    t.A[1] = Z0 + MS; t.B[1] = Y1 + MS; t.D[1] = Tb + MS;
    t.scale = -1.f; t.diag = 3.f; t.outFp32 = 0;
    mm16_k<<<dim3(8, 8, 2), 256, 0, stream>>>(t);
  }
  {
    MM16 yz{};  // Ya = Y1@T0/2 ; Z1 = T0@Z0/2
    yz.A[0] = Y1;      yz.B[0] = Tb;      yz.D[0] = Ya;
    yz.A[1] = Y1 + MS; yz.B[1] = Tb + MS; yz.D[1] = Ya + MS;
    yz.A[2] = Tb;      yz.B[2] = Z0;      yz.D[2] = Z1;
    yz.A[3] = Tb + MS; yz.B[3] = Z0 + MS; yz.D[3] = Z1 + MS;
    yz.scale = 0.5f; yz.diag = 0.f; yz.outFp32 = 0;
    mm16_k<<<dim3(8, 8, 4), 256, 0, stream>>>(yz);
  }
  {
    MM16 t{};   // T1 = 3I - Z1 @ Ya
    t.A[0] = Z1;      t.B[0] = Ya;      t.D[0] = Tb;
    t.A[1] = Z1 + MS; t.B[1] = Ya + MS; t.D[1] = Tb + MS;
    t.scale = -1.f; t.diag = 3.f; t.outFp32 = 0;
    mm16_k<<<dim3(8, 8, 2), 256, 0, stream>>>(t);
  }
  {
    MM16 yz{};  // Y1 = Ya@T1/2 ; Z0 = T1@Z1/2
    yz.A[0] = Ya;      yz.B[0] = Tb;      yz.D[0] = Y1;
    yz.A[1] = Ya + MS; yz.B[1] = Tb + MS; yz.D[1] = Y1 + MS;
    yz.A[2] = Tb;      yz.B[2] = Z1;      yz.D[2] = Z0;
    yz.A[3] = Tb + MS; yz.B[3] = Z1 + MS; yz.D[3] = Z0 + MS;
    yz.scale = 0.5f; yz.diag = 0.f; yz.outFp32 = 0;
    mm16_k<<<dim3(8, 8, 4), 256, 0, stream>>>(yz);
  }
  {
    MM16 t{};   // T2 = 3I - Z0 @ Y1
    t.A[0] = Z0;      t.B[0] = Y1;      t.D[0] = Tb;
    t.A[1] = Z0 + MS; t.B[1] = Y1 + MS; t.D[1] = Tb + MS;
    t.scale = -1.f; t.diag = 3.f; t.outFp32 = 0;
    mm16_k<<<dim3(8, 8, 2), 256, 0, stream>>>(t);
  }
  {
    MM16 zf{};  // Zf = T2 @ Z0 / 2  (fp32)
    zf.A[0] = Tb;      zf.B[0] = Z0;      zf.D[0] = Zf;
    zf.A[1] = Tb + MS; zf.B[1] = Z0 + MS; zf.D[1] = Zf + MS;
    zf.scale = 0.5f; zf.diag = 0.f; zf.outFp32 = 1;
    mm16_k<<<dim3(8, 8, 2), 256, 0, stream>>>(zf);
  }

  // symmetrize+split Zf
  symsplit_k<<<dim3(1024, 2), 256, 0, stream>>>(Zf, Zfsh, Zfsl);

  // P_b = Zfs_b @ An_b ; Q_b = Zfs_b @ Zfs_b
  MMS pq{};
  for (int b = 0; b < 2; ++b) {
    pq.Ah[b] = Zfsh + b * MS; pq.Al[b] = Zfsl + b * MS;
    pq.Bh[b] = Anh + b * MS;  pq.Bl[b] = Anl + b * MS;
    pq.Dh[b] = Ph + b * MS;   pq.Dl[b] = Pl + b * MS;
    pq.Ah[2 + b] = Zfsh + b * MS; pq.Al[2 + b] = Zfsl + b * MS;
    pq.Bh[2 + b] = Zfsh + b * MS; pq.Bl[2 + b] = Zfsl + b * MS;
    pq.Dh[2 + b] = Qh + b * MS;   pq.Dl[2 + b] = Ql + b * MS;
  }
  pq.scale = 1.f;
  mmsplit_k<<<dim3(8, 8, 4), 256, 0, stream>>>(pq);

  // Zr_b = 1.5 Zfs_b - 0.5 P_b @ Q_b  (fp32 out into Zf)
  MMS zr{};
  for (int b = 0; b < 2; ++b) {
    zr.Ah[b] = Ph + b * MS;   zr.Al[b] = Pl + b * MS;
    zr.Bh[b] = Qh + b * MS;   zr.Bl[b] = Ql + b * MS;
    zr.Eh[b] = Zfsh + b * MS; zr.El[b] = Zfsl + b * MS;
    zr.D32[b] = Zf + b * MS;
  }
  zr.scale = -0.5f; zr.beta = 1.5f;
  mmsplit_k<<<dim3(8, 8, 2), 256, 0, stream>>>(zr);

  // symmetrize+split Zr
  symsplit_k<<<dim3(1024, 2), 256, 0, stream>>>(Zf, Zrsh, Zrsl);

  // W2 = An_s @ Zrs_s (split out)
  MMS wv{};
  wv.Ah[0] = Anh + MS;  wv.Al[0] = Anl + MS;
  wv.Bh[0] = Zrsh + MS; wv.Bl[0] = Zrsl + MS;
  wv.Dh[0] = W2h; wv.Dl[0] = W2l;
  wv.scale = 1.f;
  mmsplit_k<<<dim3(8, 8, 1), 256, 0, stream>>>(wv);

  // M = coef * W2 @ Zrs_c (bf16 out)
  MMS mv{};
  mv.Ah[0] = W2h;  mv.Al[0] = W2l;
  mv.Bh[0] = Zrsh; mv.Bl[0] = Zrsl;
  mv.Db[0] = Mb;
  mv.scale = 1.f; mv.coefPtr = coef;
  mmsplit_k<<<dim3(8, 8, 1), 256, 0, stream>>>(mv);

  mconst_k<<<64, 256, 0, stream>>>(Mb, sums, mconst);
  apply_mfma<<<dim3(4, 128), 256, 0, stream>>>(fcb, Mb, mconst, Xc, out);
}

// Round 6
// 283.350 us; speedup vs baseline: 4.6985x; 1.0242x over previous
//
#include <hip/hip_runtime.h>
#include <math.h>

#define NPIX 16384      // H*W
#define CCH  512        // channels
#define MS   262144     // 512*512

typedef unsigned short u16;
typedef unsigned int u32;
typedef __attribute__((ext_vector_type(8))) short bf16x8;   // 8 bf16 = 4 VGPR
typedef __attribute__((ext_vector_type(4))) float f32x4;

__device__ __forceinline__ u16 f2bf(float f) {
  u32 u = __builtin_bit_cast(u32, f);
  u += 0x7fffu + ((u >> 16) & 1u);    // round-to-nearest-even
  return (u16)(u >> 16);
}
__device__ __forceinline__ float b2f(u16 h) {
  u32 u = ((u32)h) << 16;
  return __builtin_bit_cast(float, u);
}

typedef const __attribute__((address_space(1))) u32* gp_t;
typedef __attribute__((address_space(3))) u32* lp_t;
__device__ __forceinline__ void gl_lds16(const void* g, void* l) {
  __builtin_amdgcn_global_load_lds((gp_t)g, (lp_t)l, 16, 0, 0);
}

// ---- Kt=128 staged tile, XOR chunk swizzle (LDS row = 128 bf16 = 16x16B chunks)
__device__ __forceinline__ void stage4(const u16* tile, size_t stride, int rl,
                                       int k0, u16* lds, int lane) {
  int lr = lane >> 4;                               // 4 rows per instruction
  int cg2 = (lane & 15) ^ ((rl + lr) & 15);         // swizzled global chunk
  gl_lds16(tile + (size_t)(rl + lr) * stride + k0 + cg2 * 8,
           lds + (size_t)rl * 128);
}
__device__ __forceinline__ bf16x8 fragld(const u16* lds, int row, int cl) {
  return *(const bf16x8*)&lds[(size_t)row * 128 + (size_t)((cl ^ (row & 15)) << 3)];
}

// ---- Kt=64 variants (LDS row = 64 bf16 = 8x16B chunks); 8 rows per gl_lds16
__device__ __forceinline__ void stage8_64(const u16* tile, size_t stride, int rl,
                                          int k0, u16* lds, int lane) {
  int lr = lane >> 3;                               // 8 rows per instruction
  int cg2 = (lane & 7) ^ ((rl + lr) & 7);           // swizzled global chunk
  gl_lds16(tile + (size_t)(rl + lr) * stride + k0 + cg2 * 8,
           lds + (size_t)rl * 64);
}
__device__ __forceinline__ bf16x8 fragld64(const u16* lds, int row, int cl) {
  return *(const bf16x8*)&lds[(size_t)row * 64 + (size_t)((cl ^ (row & 7)) << 3)];
}

// ================= prep: one pass over X -> colsums, fct (bf16 [c][n]), fcb (bf16 [n][c])
__global__ __launch_bounds__(256) void prep_k(const float* __restrict__ Xc,
                                              const float* __restrict__ Xs,
                                              float* __restrict__ sums,
                                              u16* __restrict__ fct,
                                              u16* __restrict__ fcb) {
  int b = blockIdx.z;
  const float* X = b ? Xs : Xc;
  u16* outT = fct + (size_t)b * ((size_t)CCH * NPIX);
  __shared__ float T[64][65];
  __shared__ float red2[64][4];
  int n0 = blockIdx.x * 64, c0 = blockIdx.y * 64;
  int t = threadIdx.x;
  int cr = t & 15, nr = t >> 4;
  #pragma unroll
  for (int rr = 0; rr < 4; ++rr) {
    int n = nr + rr * 16;
    float4 v = *(const float4*)&X[(size_t)(n0 + n) * CCH + c0 + cr * 4];
    T[n][cr * 4 + 0] = v.x;
    T[n][cr * 4 + 1] = v.y;
    T[n][cr * 4 + 2] = v.z;
    T[n][cr * 4 + 3] = v.w;
    if (b == 0) {
      ushort4 q;
      q.x = f2bf(v.x); q.y = f2bf(v.y); q.z = f2bf(v.z); q.w = f2bf(v.w);
      *(ushort4*)&fcb[(size_t)(n0 + n) * CCH + c0 + cr * 4] = q;
    }
  }
  __syncthreads();
  int cl = t >> 2, np = (t & 3) * 16;
  size_t obase = (size_t)(c0 + cl) * NPIX + n0 + np;
  float s = 0.f;
  #pragma unroll
  for (int i = 0; i < 16; i += 4) {
    float v0 = T[np + i + 0][cl], v1 = T[np + i + 1][cl];
    float v2 = T[np + i + 2][cl], v3 = T[np + i + 3][cl];
    s += v0 + v1 + v2 + v3;
    ushort4 o;
    o.x = f2bf(v0); o.y = f2bf(v1); o.z = f2bf(v2); o.w = f2bf(v3);
    *(ushort4*)&outT[obase + i] = o;
  }
  red2[cl][t & 3] = s;
  __syncthreads();
  if (t < 64) {
    float cs = red2[t][0] + red2[t][1] + red2[t][2] + red2[t][3];
    atomicAdd(&sums[b * CCH + c0 + t], cs);
  }
}

// ================= Gram partials: 16 pairs x 16 kc x 2 batches = 512 blocks = 2/CU
// K=1024 per block; 2-phase double-buffered staging; plain stores to Gp.
__global__ __launch_bounds__(256, 2) void gram_part(const u16* __restrict__ fct,
                                                    float* __restrict__ Gp) {
  int kc = blockIdx.x;               // 0..15, K chunk of 1024
  int pair = blockIdx.y;             // 0..15
  int b = blockIdx.z;
  int bi = pair >> 2, bj = pair & 3;
  const u16* Xb = fct + (size_t)b * ((size_t)CCH * NPIX);
  __shared__ u16 As[2][128 * 64];    // 2 x 16 KB
  __shared__ u16 Bs[2][128 * 64];    // 2 x 16 KB
  int tid = threadIdx.x, w = tid >> 6, lane = tid & 63;
  int qm = w & 1, qn = w >> 1;
  const u16* ssrc = (w < 2) ? Xb + (size_t)(bi * 128) * NPIX
                            : Xb + (size_t)(bj * 128) * NPIX;
  int rbase = (w & 1) * 64;
  f32x4 acc[4][4];
  #pragma unroll
  for (int t = 0; t < 4; ++t)
    #pragma unroll
    for (int u = 0; u < 4; ++u) acc[t][u] = (f32x4)(0.f);

  #pragma unroll
  for (int i = 0; i < 8; ++i)
    stage8_64(ssrc, NPIX, rbase + i * 8, kc * 1024, (w < 2) ? As[0] : Bs[0], lane);
  __syncthreads();

  for (int st = 0; st < 16; ++st) {
    int cur = st & 1;
    if (st < 15) {
      int k0n = kc * 1024 + (st + 1) * 64;
      #pragma unroll
      for (int i = 0; i < 8; ++i)
        stage8_64(ssrc, NPIX, rbase + i * 8, k0n,
                  (w < 2) ? As[cur ^ 1] : Bs[cur ^ 1], lane);
    }
    #pragma unroll
    for (int s = 0; s < 2; ++s) {
      int cl = s * 4 + (lane >> 4);
      bf16x8 a[4], bb[4];
      #pragma unroll
      for (int t = 0; t < 4; ++t) a[t] = fragld64(As[cur], qm * 64 + t * 16 + (lane & 15), cl);
      #pragma unroll
      for (int u = 0; u < 4; ++u) bb[u] = fragld64(Bs[cur], qn * 64 + u * 16 + (lane & 15), cl);
      #pragma unroll
      for (int t = 0; t < 4; ++t)
        #pragma unroll
        for (int u = 0; u < 4; ++u)
          acc[t][u] = __builtin_amdgcn_mfma_f32_16x16x32_bf16(a[t], bb[u], acc[t][u], 0, 0, 0);
    }
    __syncthreads();
  }
  size_t tbase = ((size_t)(b * 16 + kc) * 16 + pair) * 16384;
  #pragma unroll
  for (int t = 0; t < 4; ++t) {
    int row0 = qm * 64 + t * 16 + (lane >> 4) * 4;
    #pragma unroll
    for (int u = 0; u < 4; ++u) {
      int col = qn * 64 + u * 16 + (lane & 15);
      #pragma unroll
      for (int r4 = 0; r4 < 4; ++r4)
        Gp[tbase + (size_t)(row0 + r4) * 128 + col] = acc[t][u][r4];
    }
  }
}

// ================= reduce partials + cov = (G - s s^T/N)/(N-1) + eps I ; rowsum |.|
__global__ __launch_bounds__(256) void gram_reduce(const float* __restrict__ Gp,
                                                   const float* __restrict__ sums,
                                                   float* __restrict__ cov,
                                                   float* __restrict__ rowsum) {
  int idx = blockIdx.x * 256 + threadIdx.x;   // 0 .. 2*MS-1
  int b = idx >> 18;
  int ij = idx & (MS - 1);
  int i = ij >> 9, j = ij & 511;
  int pair = ((i >> 7) << 2) | (j >> 7);
  int lij = ((i & 127) << 7) | (j & 127);
  size_t base = ((size_t)(b * 16) * 16 + pair) * 16384 + lij;
  float g = 0.f;
  #pragma unroll
  for (int kc = 0; kc < 16; ++kc)
    g += Gp[base + (size_t)kc * (16 * 16384)];
  const float* s = sums + b * CCH;
  float v = (g - s[i] * s[j] * (1.f / (float)NPIX)) * (1.f / (float)(NPIX - 1));
  if (i == j) v += 1e-8f;
  cov[idx] = v;
  __shared__ float red[256];
  int t = threadIdx.x;
  red[t] = fabsf(v);
  __syncthreads();
  for (int st = 128; st > 0; st >>= 1) {
    if (t < st) red[t] += red[t + st];
    __syncthreads();
  }
  if (t == 0) atomicAdd(&rowsum[b * CCH + i], red[0]);
}

// ================= NS init (+ fused norm/coef): An split; Z0 = (c/2)(3I-Â), c^2=2
__global__ __launch_bounds__(256) void nsinit_k(const float* __restrict__ cov,
                                                const float* __restrict__ rowsum,
                                                float* __restrict__ snorm,
                                                float* __restrict__ coef,
                                                u16* __restrict__ Anh,
                                                u16* __restrict__ Anl,
                                                u16* __restrict__ Z0) {
  __shared__ float red[256];
  int tid = threadIdx.x, blk = blockIdx.x;
  float m = fmaxf(rowsum[tid], rowsum[tid + 256]);
  red[tid] = m; __syncthreads();
  for (int s = 128; s > 0; s >>= 1) {
    if (tid < s) red[tid] = fmaxf(red[tid], red[tid + s]);
    __syncthreads();
  }
  float snc = red[0]; __syncthreads();
  m = fmaxf(rowsum[512 + tid], rowsum[768 + tid]);
  red[tid] = m; __syncthreads();
  for (int s = 128; s > 0; s >>= 1) {
    if (tid < s) red[tid] = fmaxf(red[tid], red[tid + s]);
    __syncthreads();
  }
  float sns = red[0];
  if (blk == 0 && tid == 0) {
    snorm[0] = snc; snorm[1] = sns;
    coef[0] = 0.8f * sqrtf(sns / snc);
  }
  int idx = blk * 256 + tid;                 // 0 .. 2*MS-1 (grid 2048)
  int b = idx >> 18;
  int ij = idx & (MS - 1);
  int diag = (ij >> 9) == (ij & 511);
  float av = cov[idx] * (b ? 1.f / sns : 1.f / snc);
  u16 hi = f2bf(av);
  Anh[idx] = hi;
  Anl[idx] = f2bf(av - b2f(hi));
  float t0 = (diag ? 3.f - av : -av) * 0.70710678f;   // boosted first step
  Z0[idx] = f2bf(t0);
}

// ================= plain bf16 NS matmul, 64x64 tiles, Kt=128 dbuf: D = diag*I + scale*(A @ B^T)
struct MM16 {
  const u16* A[4];
  const u16* B[4];
  void* D[4];
  float scale, diag;
  int outFp32;
};

__global__ __launch_bounds__(256) void mm16_k(MM16 args) {
  int z = blockIdx.z;
  const u16* __restrict__ A = args.A[z];
  const u16* __restrict__ B = args.B[z];
  int bi = blockIdx.y, bj = blockIdx.x;
  __shared__ u16 As[2][64 * 128];    // 2 x 16 KB
  __shared__ u16 Bs[2][64 * 128];    // 2 x 16 KB
  int tid = threadIdx.x, w = tid >> 6, lane = tid & 63;
  int qm = w & 1, qn = w >> 1;
  const u16* ssrc = ((w < 2) ? A + (size_t)(bi * 64) * CCH : B + (size_t)(bj * 64) * CCH);
  int rbase = (w & 1) * 32;
  f32x4 acc[2][2];
  #pragma unroll
  for (int t = 0; t < 2; ++t)
    #pragma unroll
    for (int u = 0; u < 2; ++u) acc[t][u] = (f32x4)(0.f);

  #pragma unroll
  for (int i = 0; i < 8; ++i)
    stage4(ssrc, CCH, rbase + i * 4, 0, (w < 2) ? As[0] : Bs[0], lane);
  __syncthreads();

  for (int st = 0; st < 4; ++st) {
    int cur = st & 1;
    if (st < 3) {
      #pragma unroll
      for (int i = 0; i < 8; ++i)
        stage4(ssrc, CCH, rbase + i * 4, (st + 1) * 128,
               (w < 2) ? As[cur ^ 1] : Bs[cur ^ 1], lane);
    }
    #pragma unroll
    for (int s = 0; s < 4; ++s) {
      int cl = s * 4 + (lane >> 4);
      bf16x8 a[2], bb[2];
      #pragma unroll
      for (int t = 0; t < 2; ++t) a[t] = fragld(As[cur], qm * 32 + t * 16 + (lane & 15), cl);
      #pragma unroll
      for (int u = 0; u < 2; ++u) bb[u] = fragld(Bs[cur], qn * 32 + u * 16 + (lane & 15), cl);
      #pragma unroll
      for (int t = 0; t < 2; ++t)
        #pragma unroll
        for (int u = 0; u < 2; ++u)
          acc[t][u] = __builtin_amdgcn_mfma_f32_16x16x32_bf16(a[t], bb[u], acc[t][u], 0, 0, 0);
    }
    __syncthreads();
  }
  float sc = args.scale;
  #pragma unroll
  for (int t = 0; t < 2; ++t) {
    int row0 = bi * 64 + qm * 32 + t * 16 + (lane >> 4) * 4;
    #pragma unroll
    for (int u = 0; u < 2; ++u) {
      int col = bj * 64 + qn * 32 + u * 16 + (lane & 15);
      #pragma unroll
      for (int r4 = 0; r4 < 4; ++r4) {
        float v = sc * acc[t][u][r4];
        if (row0 + r4 == col) v += args.diag;
        size_t o = (size_t)(row0 + r4) * CCH + col;
        if (args.outFp32) ((float*)args.D[z])[o] = v;
        else ((u16*)args.D[z])[o] = f2bf(v);
      }
    }
  }
}

// ================= zfsym: Zfs = sym(0.5 * T2 @ Z0^T), split hi/lo, direct.
// Triangle blocks: each computes mirror tiles (bi,bj) and (bj,bi), symmetrizes
// in-register via LDS transpose. Bit-identical to mm16(zf)+symsplit:
// same ascending-k MFMA order; v = 0.5f*(0.5f*a + 0.5f*bT) identical fp32 ops.
__global__ __launch_bounds__(256, 2) void zfsym_k(const u16* __restrict__ Tb,
                                                  const u16* __restrict__ Z0,
                                                  u16* __restrict__ Oh_,
                                                  u16* __restrict__ Ol_) {
  int z = blockIdx.z;
  int p = blockIdx.x;                 // 0..35 triangle pair
  int bi = 0, pp = p;
  while (pp >= 8 - bi) { pp -= 8 - bi; ++bi; }
  int bj = bi + pp;
  const u16* A = Tb + (size_t)z * MS;
  const u16* B = Z0 + (size_t)z * MS;
  u16* Oh = Oh_ + (size_t)z * MS;
  u16* Ol = Ol_ + (size_t)z * MS;
  __shared__ u16 smem[32768];         // 4 panels x 2 bufs x 4096 u16 = 64 KB
  int tid = threadIdx.x, w = tid >> 6, lane = tid & 63;
  int qm = w & 1, qn = w >> 1;
  // panels: 0=A[bi] 1=B[bj] 2=A[bj] 3=B[bi]; wave w stages panel w
  const u16* ssrc = (w == 0) ? A + (size_t)(bi * 64) * CCH
                  : (w == 1) ? B + (size_t)(bj * 64) * CCH
                  : (w == 2) ? A + (size_t)(bj * 64) * CCH
                             : B + (size_t)(bi * 64) * CCH;
  u16* sbase = smem + w * 8192;
  f32x4 acc1[2][2], acc2[2][2];
  #pragma unroll
  for (int t = 0; t < 2; ++t)
    #pragma unroll
    for (int u = 0; u < 2; ++u) { acc1[t][u] = (f32x4)(0.f); acc2[t][u] = (f32x4)(0.f); }

  #pragma unroll
  for (int i = 0; i < 8; ++i) stage8_64(ssrc, CCH, i * 8, 0, sbase, lane);
  __syncthreads();
  for (int st = 0; st < 8; ++st) {
    int cur = st & 1;
    if (st < 7) {
      u16* sdst = sbase + (cur ^ 1) * 4096;
      #pragma unroll
      for (int i = 0; i < 8; ++i) stage8_64(ssrc, CCH, i * 8, (st + 1) * 64, sdst, lane);
    }
    u16* P0 = smem + 0 * 8192 + cur * 4096;
    u16* P1 = smem + 1 * 8192 + cur * 4096;
    u16* P2 = smem + 2 * 8192 + cur * 4096;
    u16* P3 = smem + 3 * 8192 + cur * 4096;
    #pragma unroll
    for (int s = 0; s < 2; ++s) {
      int cl = s * 4 + (lane >> 4);
      bf16x8 a1[2], b1[2], a2[2], b2[2];
      #pragma unroll
      for (int t = 0; t < 2; ++t) a1[t] = fragld64(P0, qm * 32 + t * 16 + (lane & 15), cl);
      #pragma unroll
      for (int u = 0; u < 2; ++u) b1[u] = fragld64(P1, qn * 32 + u * 16 + (lane & 15), cl);
      #pragma unroll
      for (int t = 0; t < 2; ++t)
        #pragma unroll
        for (int u = 0; u < 2; ++u)
          acc1[t][u] = __builtin_amdgcn_mfma_f32_16x16x32_bf16(a1[t], b1[u], acc1[t][u], 0, 0, 0);
      #pragma unroll
      for (int t = 0; t < 2; ++t) a2[t] = fragld64(P2, qm * 32 + t * 16 + (lane & 15), cl);
      #pragma unroll
      for (int u = 0; u < 2; ++u) b2[u] = fragld64(P3, qn * 32 + u * 16 + (lane & 15), cl);
      #pragma unroll
      for (int t = 0; t < 2; ++t)
        #pragma unroll
        for (int u = 0; u < 2; ++u)
          acc2[t][u] = __builtin_amdgcn_mfma_f32_16x16x32_bf16(a2[t], b2[u], acc2[t][u], 0, 0, 0);
    }
    __syncthreads();
  }
  // epilogue: transpose sc*acc2 via LDS, symmetrize, split, dual store
  const float sc = 0.5f;
  float* fs = (float*)smem;           // 64x65 fp32 = 16.6 KB
  #pragma unroll
  for (int t = 0; t < 2; ++t) {
    int r20 = qm * 32 + t * 16 + (lane >> 4) * 4;
    #pragma unroll
    for (int u = 0; u < 2; ++u) {
      int c2 = qn * 32 + u * 16 + (lane & 15);
      #pragma unroll
      for (int r4 = 0; r4 < 4; ++r4)
        fs[(r20 + r4) * 65 + c2] = sc * acc2[t][u][r4];
    }
  }
  __syncthreads();
  #pragma unroll
  for (int t = 0; t < 2; ++t) {
    int r0 = qm * 32 + t * 16 + (lane >> 4) * 4;
    #pragma unroll
    for (int u = 0; u < 2; ++u) {
      int c = qn * 32 + u * 16 + (lane & 15);
      #pragma unroll
      for (int r4 = 0; r4 < 4; ++r4) {
        int r = r0 + r4;
        float v = 0.5f * (sc * acc1[t][u][r4] + fs[c * 65 + r]);
        u16 hh = f2bf(v), ll = f2bf(v - b2f(hh));
        size_t o1 = (size_t)(bi * 64 + r) * CCH + (bj * 64 + c);
        Oh[o1] = hh; Ol[o1] = ll;
        if (bi != bj) {
          size_t o2 = (size_t)(bj * 64 + c) * CCH + (bi * 64 + r);
          Oh[o2] = hh; Ol[o2] = ll;
        }
      }
    }
  }
}

// ================= split-bf16 matmul (~fp32 quality), 64x64 tiles, Kt=64 dbuf
struct MMS {
  const u16 *Ah[4], *Al[4], *Bh[4], *Bl[4];
  const u16 *Eh[4], *El[4];
  u16 *Dh[4], *Dl[4];
  float *D32[4];
  u16 *Db[4];
  float scale, beta;
  const float* coefPtr;
};

__global__ __launch_bounds__(256) void mmsplit_k(MMS args) {
  int z = blockIdx.z;
  int bi = blockIdx.y, bj = blockIdx.x;
  __shared__ u16 Ash[2][64 * 64], Asl[2][64 * 64];   // 4 x 8 KB
  __shared__ u16 Bsh[2][64 * 64], Bsl[2][64 * 64];   // 4 x 8 KB
  int tid = threadIdx.x, w = tid >> 6, lane = tid & 63;
  int qm = w & 1, qn = w >> 1;
  const u16* sp = (w == 0) ? args.Ah[z] : (w == 1) ? args.Al[z]
                : (w == 2) ? args.Bh[z] : args.Bl[z];
  const u16* ssrc = sp + (size_t)(((w < 2) ? bi : bj) * 64) * CCH;
  u16* sd0 = (w == 0) ? Ash[0] : (w == 1) ? Asl[0] : (w == 2) ? Bsh[0] : Bsl[0];
  u16* sd1 = (w == 0) ? Ash[1] : (w == 1) ? Asl[1] : (w == 2) ? Bsh[1] : Bsl[1];
  f32x4 acc[2][2];
  #pragma unroll
  for (int t = 0; t < 2; ++t)
    #pragma unroll
    for (int u = 0; u < 2; ++u) acc[t][u] = (f32x4)(0.f);

  #pragma unroll
  for (int i = 0; i < 8; ++i)
    stage8_64(ssrc, CCH, i * 8, 0, sd0, lane);
  __syncthreads();

  for (int st = 0; st < 8; ++st) {
    int cur = st & 1;
    if (st < 7) {
      u16* sdn = cur ? sd0 : sd1;
      #pragma unroll
      for (int i = 0; i < 8; ++i)
        stage8_64(ssrc, CCH, i * 8, (st + 1) * 64, sdn, lane);
    }
    #pragma unroll
    for (int s = 0; s < 2; ++s) {
      int cl = s * 4 + (lane >> 4);
      bf16x8 ah[2], al[2], bh[2], bl[2];
      #pragma unroll
      for (int t = 0; t < 2; ++t) {
        int row = qm * 32 + t * 16 + (lane & 15);
        ah[t] = fragld64(Ash[cur], row, cl);
        al[t] = fragld64(Asl[cur], row, cl);
      }
      #pragma unroll
      for (int u = 0; u < 2; ++u) {
        int row = qn * 32 + u * 16 + (lane & 15);
        bh[u] = fragld64(Bsh[cur], row, cl);
        bl[u] = fragld64(Bsl[cur], row, cl);
      }
      #pragma unroll
      for (int t = 0; t < 2; ++t)
        #pragma unroll
        for (int u = 0; u < 2; ++u) {
          acc[t][u] = __builtin_amdgcn_mfma_f32_16x16x32_bf16(ah[t], bh[u], acc[t][u], 0, 0, 0);
          acc[t][u] = __builtin_amdgcn_mfma_f32_16x16x32_bf16(ah[t], bl[u], acc[t][u], 0, 0, 0);
          acc[t][u] = __builtin_amdgcn_mfma_f32_16x16x32_bf16(al[t], bh[u], acc[t][u], 0, 0, 0);
        }
    }
    __syncthreads();
  }
  float sc = args.scale;
  if (args.coefPtr) sc *= *args.coefPtr;
  #pragma unroll
  for (int t = 0; t < 2; ++t) {
    int row0 = bi * 64 + qm * 32 + t * 16 + (lane >> 4) * 4;
    #pragma unroll
    for (int u = 0; u < 2; ++u) {
      int col = bj * 64 + qn * 32 + u * 16 + (lane & 15);
      #pragma unroll
      for (int r4 = 0; r4 < 4; ++r4) {
        size_t o = (size_t)(row0 + r4) * CCH + col;
        float v = sc * acc[t][u][r4];
        if (args.beta != 0.f) v += args.beta * (b2f(args.Eh[z][o]) + b2f(args.El[z][o]));
        if (args.D32[z]) args.D32[z][o] = v;
        if (args.Dh[z]) {
          u16 h = f2bf(v);
          args.Dh[z][o] = h;
          args.Dl[z][o] = f2bf(v - b2f(h));
        }
        if (args.Db[z]) args.Db[z][o] = f2bf(v);
      }
    }
  }
}

// ================= zrsym: Zrs = sym(1.5 Zfs - 0.5 P@Q^T), split hi/lo, direct.
// Dual-tile split-bf16 (8 LDS panels, single-buffered Kt=64). Bit-identical to
// mmsplit(zr)+symsplit: same k-order/triad order; z = sc*acc + beta*(Eh+El);
// v = 0.5f*(z1 + z2T).
__global__ __launch_bounds__(256, 2) void zrsym_k(const u16* __restrict__ Ph_,
                                                  const u16* __restrict__ Pl_,
                                                  const u16* __restrict__ Qh_,
                                                  const u16* __restrict__ Ql_,
                                                  const u16* __restrict__ Eh_,
                                                  const u16* __restrict__ El_,
                                                  u16* __restrict__ Oh_,
                                                  u16* __restrict__ Ol_) {
  int z = blockIdx.z;
  int p = blockIdx.x;                 // 0..35
  int bi = 0, pp = p;
  while (pp >= 8 - bi) { pp -= 8 - bi; ++bi; }
  int bj = bi + pp;
  const u16* Ph = Ph_ + (size_t)z * MS;
  const u16* Pl = Pl_ + (size_t)z * MS;
  const u16* Qh = Qh_ + (size_t)z * MS;
  const u16* Ql = Ql_ + (size_t)z * MS;
  const u16* Eh = Eh_ + (size_t)z * MS;
  const u16* El = El_ + (size_t)z * MS;
  u16* Oh = Oh_ + (size_t)z * MS;
  u16* Ol = Ol_ + (size_t)z * MS;
  __shared__ u16 smem[32768];         // 8 panels x 4096 u16, single-buffered
  int tid = threadIdx.x, w = tid >> 6, lane = tid & 63;
  int qm = w & 1, qn = w >> 1;
  // panels: 0=Ph[bi] 1=Pl[bi] 2=Qh[bj] 3=Ql[bj] 4=Ph[bj] 5=Pl[bj] 6=Qh[bi] 7=Ql[bi]
  const u16* s1 = (w == 0) ? Ph + (size_t)(bi * 64) * CCH
                : (w == 1) ? Pl + (size_t)(bi * 64) * CCH
                : (w == 2) ? Qh + (size_t)(bj * 64) * CCH
                           : Ql + (size_t)(bj * 64) * CCH;
  const u16* s2 = (w == 0) ? Ph + (size_t)(bj * 64) * CCH
                : (w == 1) ? Pl + (size_t)(bj * 64) * CCH
                : (w == 2) ? Qh + (size_t)(bi * 64) * CCH
                           : Ql + (size_t)(bi * 64) * CCH;
  u16* d1 = smem + w * 4096;
  u16* d2 = smem + (w + 4) * 4096;
  f32x4 acc1[2][2], acc2[2][2];
  #pragma unroll
  for (int t = 0; t < 2; ++t)
    #pragma unroll
    for (int u = 0; u < 2; ++u) { acc1[t][u] = (f32x4)(0.f); acc2[t][u] = (f32x4)(0.f); }

  for (int st = 0; st < 8; ++st) {
    __syncthreads();                  // protect LDS from previous step's reads
    #pragma unroll
    for (int i = 0; i < 8; ++i) stage8_64(s1, CCH, i * 8, st * 64, d1, lane);
    #pragma unroll
    for (int i = 0; i < 8; ++i) stage8_64(s2, CCH, i * 8, st * 64, d2, lane);
    __syncthreads();                  // vmcnt drained before barrier -> staged data visible
    #pragma unroll
    for (int s = 0; s < 2; ++s) {
      int cl = s * 4 + (lane >> 4);
      bf16x8 ah[2], al[2], bh[2], bl[2];
      // tile1: A=P[bi](0,1) B=Q[bj](2,3)
      #pragma unroll
      for (int t = 0; t < 2; ++t) {
        int row = qm * 32 + t * 16 + (lane & 15);
        ah[t] = fragld64(smem + 0 * 4096, row, cl);
        al[t] = fragld64(smem + 1 * 4096, row, cl);
      }
      #pragma unroll
      for (int u = 0; u < 2; ++u) {
        int row = qn * 32 + u * 16 + (lane & 15);
        bh[u] = fragld64(smem + 2 * 4096, row, cl);
        bl[u] = fragld64(smem + 3 * 4096, row, cl);
      }
      #pragma unroll
      for (int t = 0; t < 2; ++t)
        #pragma unroll
        for (int u = 0; u < 2; ++u) {
          acc1[t][u] = __builtin_amdgcn_mfma_f32_16x16x32_bf16(ah[t], bh[u], acc1[t][u], 0, 0, 0);
          acc1[t][u] = __builtin_amdgcn_mfma_f32_16x16x32_bf16(ah[t], bl[u], acc1[t][u], 0, 0, 0);
          acc1[t][u] = __builtin_amdgcn_mfma_f32_16x16x32_bf16(al[t], bh[u], acc1[t][u], 0, 0, 0);
        }
      // tile2: A=P[bj](4,5) B=Q[bi](6,7)
      #pragma unroll
      for (int t = 0; t < 2; ++t) {
        int row = qm * 32 + t * 16 + (lane & 15);
        ah[t] = fragld64(smem + 4 * 4096, row, cl);
        al[t] = fragld64(smem + 5 * 4096, row, cl);
      }
      #pragma unroll
      for (int u = 0; u < 2; ++u) {
        int row = qn * 32 + u * 16 + (lane & 15);
        bh[u] = fragld64(smem + 6 * 4096, row, cl);
        bl[u] = fragld64(smem + 7 * 4096, row, cl);
      }
      #pragma unroll
      for (int t = 0; t < 2; ++t)
        #pragma unroll
        for (int u = 0; u < 2; ++u) {
          acc2[t][u] = __builtin_amdgcn_mfma_f32_16x16x32_bf16(ah[t], bh[u], acc2[t][u], 0, 0, 0);
          acc2[t][u] = __builtin_amdgcn_mfma_f32_16x16x32_bf16(ah[t], bl[u], acc2[t][u], 0, 0, 0);
          acc2[t][u] = __builtin_amdgcn_mfma_f32_16x16x32_bf16(al[t], bh[u], acc2[t][u], 0, 0, 0);
        }
    }
  }
  // epilogue
  const float sc = -0.5f, beta = 1.5f;
  float* fs = (float*)smem;
  __syncthreads();
  #pragma unroll
  for (int t = 0; t < 2; ++t) {
    int r20 = qm * 32 + t * 16 + (lane >> 4) * 4;
    #pragma unroll
    for (int u = 0; u < 2; ++u) {
      int c2 = qn * 32 + u * 16 + (lane & 15);
      #pragma unroll
      for (int r4 = 0; r4 < 4; ++r4) {
        int r2 = r20 + r4;
        size_t o2e = (size_t)(bj * 64 + r2) * CCH + (bi * 64 + c2);
        float z2 = sc * acc2[t][u][r4] + beta * (b2f(Eh[o2e]) + b2f(El[o2e]));
        fs[r2 * 65 + c2] = z2;
      }
    }
  }
  __syncthreads();
  #pragma unroll
  for (int t = 0; t < 2; ++t) {
    int r0 = qm * 32 + t * 16 + (lane >> 4) * 4;
    #pragma unroll
    for (int u = 0; u < 2; ++u) {
      int c = qn * 32 + u * 16 + (lane & 15);
      #pragma unroll
      for (int r4 = 0; r4 < 4; ++r4) {
        int r = r0 + r4;
        size_t o1 = (size_t)(bi * 64 + r) * CCH + (bj * 64 + c);
        float z1 = sc * acc1[t][u][r4] + beta * (b2f(Eh[o1]) + b2f(El[o1]));
        float v = 0.5f * (z1 + fs[c * 65 + r]);
        u16 hh = f2bf(v), ll = f2bf(v - b2f(hh));
        Oh[o1] = hh; Ol[o1] = ll;
        if (bi != bj) {
          size_t o2 = (size_t)(bj * 64 + c) * CCH + (bi * 64 + r);
          Oh[o2] = hh; Ol[o2] = ll;
        }
      }
    }
  }
}

// ================= mconst[c] = (0.8*ssum[c] - (M @ csum)[c]) / N
__global__ __launch_bounds__(256) void mconst_k(const u16* __restrict__ Mb,
                                                const float* __restrict__ sums,
                                                float* __restrict__ mconst) {
  int c = blockIdx.x * 8 + (threadIdx.x >> 5);   // grid 64
  int l = threadIdx.x & 31;
  float s = 0.f;
  #pragma unroll
  for (int k = 0; k < 16; ++k) {
    int j = l + 32 * k;
    s += b2f(Mb[(size_t)c * CCH + j]) * sums[j];
  }
  s += __shfl_down(s, 16, 32);
  s += __shfl_down(s, 8, 32);
  s += __shfl_down(s, 4, 32);
  s += __shfl_down(s, 2, 32);
  s += __shfl_down(s, 1, 32);
  if (l == 0) mconst[c] = (0.8f * sums[512 + c] - s) * (1.f / (float)NPIX);
}

// ================= apply: out = fcb @ M^T + mconst + 0.2 X   (128-tiles, Kt=64 dbuf)
__global__ __launch_bounds__(256) void apply_mfma(const u16* __restrict__ fcb,
                                                  const u16* __restrict__ Mb,
                                                  const float* __restrict__ mconst,
                                                  const float* __restrict__ X,
                                                  float* __restrict__ out) {
  int bi = blockIdx.y;    // n tile (0..127)
  int bj = blockIdx.x;    // c tile (0..3)
  __shared__ u16 As[2][128 * 64];    // 2 x 16 KB
  __shared__ u16 Bs[2][128 * 64];    // 2 x 16 KB
  int tid = threadIdx.x, w = tid >> 6, lane = tid & 63;
  int qm = w & 1, qn = w >> 1;
  const u16* ssrc = (w < 2) ? fcb + (size_t)(bi * 128) * CCH
                            : Mb + (size_t)(bj * 128) * CCH;
  int rbase = (w & 1) * 64;
  f32x4 acc[4][4];
  #pragma unroll
  for (int t = 0; t < 4; ++t)
    #pragma unroll
    for (int u = 0; u < 4; ++u) acc[t][u] = (f32x4)(0.f);

  #pragma unroll
  for (int i = 0; i < 8; ++i)
    stage8_64(ssrc, CCH, rbase + i * 8, 0, (w < 2) ? As[0] : Bs[0], lane);
  __syncthreads();

  for (int st = 0; st < 8; ++st) {
    int cur = st & 1;
    if (st < 7) {
      #pragma unroll
      for (int i = 0; i < 8; ++i)
        stage8_64(ssrc, CCH, rbase + i * 8, (st + 1) * 64,
                  (w < 2) ? As[cur ^ 1] : Bs[cur ^ 1], lane);
    }
    #pragma unroll
    for (int s = 0; s < 2; ++s) {
      int cl = s * 4 + (lane >> 4);
      bf16x8 a[4], bb[4];
      #pragma unroll
      for (int t = 0; t < 4; ++t) a[t] = fragld64(As[cur], qm * 64 + t * 16 + (lane & 15), cl);
      #pragma unroll
      for (int u = 0; u < 4; ++u) bb[u] = fragld64(Bs[cur], qn * 64 + u * 16 + (lane & 15), cl);
      #pragma unroll
      for (int t = 0; t < 4; ++t)
        #pragma unroll
        for (int u = 0; u < 4; ++u)
          acc[t][u] = __builtin_amdgcn_mfma_f32_16x16x32_bf16(a[t], bb[u], acc[t][u], 0, 0, 0);
    }
    __syncthreads();
  }
  #pragma unroll
  for (int t = 0; t < 4; ++t) {
    int row0 = bi * 128 + qm * 64 + t * 16 + (lane >> 4) * 4;
    #pragma unroll
    for (int u = 0; u < 4; ++u) {
      int col = bj * 128 + qn * 64 + u * 16 + (lane & 15);
      float cst = mconst[col];
      #pragma unroll
      for (int r4 = 0; r4 < 4; ++r4) {
        size_t o = (size_t)(row0 + r4) * CCH + col;
        out[o] = acc[t][u][r4] + cst + 0.2f * X[o];
      }
    }
  }
}

// ================================================================ launcher
extern "C" void kernel_launch(void* const* d_in, const int* in_sizes, int n_in,
                              void* d_out, int out_size, void* d_ws, size_t ws_size,
                              hipStream_t stream) {
  const float* Xc = (const float*)d_in[0];
  const float* Xs = (const float*)d_in[1];
  float* out = (float*)d_out;

  float* f = (float*)d_ws;
  float* sums   = f;                     // 1024
  float* rowsum = f + 1024;              // 1024
  float* cov    = f + 2048 + 2 * MS;     // 2*MS
  float* snorm  = cov + 2 * MS;          // 8
  float* coef   = snorm + 8;             // 8
  float* mconst = coef + 8;              // 512
  float* Zf     = mconst + 512;          // 2*MS (reserved; unused after zfsym/zrsym fusion)

  // Gram split-K partials live in d_out (dead until apply_mfma): 32 MiB exactly.
  float* Gp = (float*)d_out;

  u16* h   = (u16*)(Zf + 2 * MS);
  u16* fct = h;                          // 2*512*16384 u16 (dead after gram)
  u16* fcb = h + (size_t)2 * CCH * NPIX; // 16384*512 u16
  const size_t B2 = 2 * MS;
  u16* Anh  = fct + 0 * B2;
  u16* Anl  = fct + 1 * B2;
  u16* Y1   = fct + 2 * B2;
  u16* Ya   = fct + 3 * B2;
  u16* Z0   = fct + 4 * B2;
  u16* Z1   = fct + 5 * B2;
  u16* Tb   = fct + 6 * B2;
  u16* Zfsh = fct + 7 * B2;
  u16* Zfsl = fct + 8 * B2;
  u16* Ph   = fct + 9 * B2;
  u16* Pl   = fct + 10 * B2;
  u16* Qh   = fct + 11 * B2;
  u16* Ql   = fct + 12 * B2;
  u16* Zrsh = fct + 13 * B2;
  u16* Zrsl = fct + 14 * B2;
  u16* W2h  = fct + 15 * B2;
  u16* W2l  = W2h + MS;
  u16* Mb   = W2l + MS;

  hipMemsetAsync(d_ws, 0, 2048 * sizeof(float), stream);

  prep_k<<<dim3(256, 8, 2), 256, 0, stream>>>(Xc, Xs, sums, fct, fcb);
  gram_part<<<dim3(16, 16, 2), 256, 0, stream>>>(fct, Gp);
  gram_reduce<<<2048, 256, 0, stream>>>(Gp, sums, cov, rowsum);
  nsinit_k<<<2048, 256, 0, stream>>>(cov, rowsum, snorm, coef, Anh, Anl, Z0);

  // NS: boosted first step (in nsinit) + 2 full iterations + final Z-update
  {
    MM16 y1{};
    y1.A[0] = Anh;      y1.B[0] = Z0;      y1.D[0] = Y1;
    y1.A[1] = Anh + MS; y1.B[1] = Z0 + MS; y1.D[1] = Y1 + MS;
    y1.scale = 1.f; y1.diag = 0.f; y1.outFp32 = 0;
    mm16_k<<<dim3(8, 8, 2), 256, 0, stream>>>(y1);
  }
  {
    MM16 t{};   // T0 = 3I - Z0 @ Y1
    t.A[0] = Z0;      t.B[0] = Y1;      t.D[0] = Tb;
    t.A[1] = Z0 + MS; t.B[1] = Y1 + MS; t.D[1] = Tb + MS;
    t.scale = -1.f; t.diag = 3.f; t.outFp32 = 0;
    mm16_k<<<dim3(8, 8, 2), 256, 0, stream>>>(t);
  }
  {
    MM16 yz{};  // Ya = Y1@T0/2 ; Z1 = T0@Z0/2
    yz.A[0] = Y1;      yz.B[0] = Tb;      yz.D[0] = Ya;
    yz.A[1] = Y1 + MS; yz.B[1] = Tb + MS; yz.D[1] = Ya + MS;
    yz.A[2] = Tb;      yz.B[2] = Z0;      yz.D[2] = Z1;
    yz.A[3] = Tb + MS; yz.B[3] = Z0 + MS; yz.D[3] = Z1 + MS;
    yz.scale = 0.5f; yz.diag = 0.f; yz.outFp32 = 0;
    mm16_k<<<dim3(8, 8, 4), 256, 0, stream>>>(yz);
  }
  {
    MM16 t{};   // T1 = 3I - Z1 @ Ya
    t.A[0] = Z1;      t.B[0] = Ya;      t.D[0] = Tb;
    t.A[1] = Z1 + MS; t.B[1] = Ya + MS; t.D[1] = Tb + MS;
    t.scale = -1.f; t.diag = 3.f; t.outFp32 = 0;
    mm16_k<<<dim3(8, 8, 2), 256, 0, stream>>>(t);
  }
  {
    MM16 yz{};  // Y1 = Ya@T1/2 ; Z0 = T1@Z1/2
    yz.A[0] = Ya;      yz.B[0] = Tb;      yz.D[0] = Y1;
    yz.A[1] = Ya + MS; yz.B[1] = Tb + MS; yz.D[1] = Y1 + MS;
    yz.A[2] = Tb;      yz.B[2] = Z1;      yz.D[2] = Z0;
    yz.A[3] = Tb + MS; yz.B[3] = Z1 + MS; yz.D[3] = Z0 + MS;
    yz.scale = 0.5f; yz.diag = 0.f; yz.outFp32 = 0;
    mm16_k<<<dim3(8, 8, 4), 256, 0, stream>>>(yz);
  }
  {
    MM16 t{};   // T2 = 3I - Z0 @ Y1
    t.A[0] = Z0;      t.B[0] = Y1;      t.D[0] = Tb;
    t.A[1] = Z0 + MS; t.B[1] = Y1 + MS; t.D[1] = Tb + MS;
    t.scale = -1.f; t.diag = 3.f; t.outFp32 = 0;
    mm16_k<<<dim3(8, 8, 2), 256, 0, stream>>>(t);
  }

  // Zfs = sym(T2 @ Z0 / 2), split -> Zfsh/Zfsl  (replaces zf + symsplit)
  zfsym_k<<<dim3(36, 1, 2), 256, 0, stream>>>(Tb, Z0, Zfsh, Zfsl);

  // P_b = Zfs_b @ An_b ; Q_b = Zfs_b @ Zfs_b
  MMS pq{};
  for (int b = 0; b < 2; ++b) {
    pq.Ah[b] = Zfsh + b * MS; pq.Al[b] = Zfsl + b * MS;
    pq.Bh[b] = Anh + b * MS;  pq.Bl[b] = Anl + b * MS;
    pq.Dh[b] = Ph + b * MS;   pq.Dl[b] = Pl + b * MS;
    pq.Ah[2 + b] = Zfsh + b * MS; pq.Al[2 + b] = Zfsl + b * MS;
    pq.Bh[2 + b] = Zfsh + b * MS; pq.Bl[2 + b] = Zfsl + b * MS;
    pq.Dh[2 + b] = Qh + b * MS;   pq.Dl[2 + b] = Ql + b * MS;
  }
  pq.scale = 1.f;
  mmsplit_k<<<dim3(8, 8, 4), 256, 0, stream>>>(pq);

  // Zrs = sym(1.5 Zfs - 0.5 P@Q), split -> Zrsh/Zrsl  (replaces zr + symsplit)
  zrsym_k<<<dim3(36, 1, 2), 256, 0, stream>>>(Ph, Pl, Qh, Ql, Zfsh, Zfsl, Zrsh, Zrsl);

  // W2 = An_s @ Zrs_s (split out)
  MMS wv{};
  wv.Ah[0] = Anh + MS;  wv.Al[0] = Anl + MS;
  wv.Bh[0] = Zrsh + MS; wv.Bl[0] = Zrsl + MS;
  wv.Dh[0] = W2h; wv.Dl[0] = W2l;
  wv.scale = 1.f;
  mmsplit_k<<<dim3(8, 8, 1), 256, 0, stream>>>(wv);

  // M = coef * W2 @ Zrs_c (bf16 out)
  MMS mv{};
  mv.Ah[0] = W2h;  mv.Al[0] = W2l;
  mv.Bh[0] = Zrsh; mv.Bl[0] = Zrsl;
  mv.Db[0] = Mb;
  mv.scale = 1.f; mv.coefPtr = coef;
  mmsplit_k<<<dim3(8, 8, 1), 256, 0, stream>>>(mv);

  mconst_k<<<64, 256, 0, stream>>>(Mb, sums, mconst);
  apply_mfma<<<dim3(4, 128), 256, 0, stream>>>(fcb, Mb, mconst, Xc, out);
}

// Round 7
// 273.430 us; speedup vs baseline: 4.8690x; 1.0363x over previous
//
#include <hip/hip_runtime.h>
#include <math.h>

#define NPIX 16384      // H*W
#define CCH  512        // channels
#define MS   262144     // 512*512

typedef unsigned short u16;
typedef unsigned int u32;
typedef __attribute__((ext_vector_type(8))) short bf16x8;   // 8 bf16 = 4 VGPR
typedef __attribute__((ext_vector_type(4))) float f32x4;

__device__ __forceinline__ u16 f2bf(float f) {
  u32 u = __builtin_bit_cast(u32, f);
  u += 0x7fffu + ((u >> 16) & 1u);    // round-to-nearest-even
  return (u16)(u >> 16);
}
__device__ __forceinline__ float b2f(u16 h) {
  u32 u = ((u32)h) << 16;
  return __builtin_bit_cast(float, u);
}

typedef const __attribute__((address_space(1))) u32* gp_t;
typedef __attribute__((address_space(3))) u32* lp_t;
__device__ __forceinline__ void gl_lds16(const void* g, void* l) {
  __builtin_amdgcn_global_load_lds((gp_t)g, (lp_t)l, 16, 0, 0);
}

// ---- Kt=128 staged tile, XOR chunk swizzle (LDS row = 128 bf16 = 16x16B chunks)
__device__ __forceinline__ void stage4(const u16* tile, size_t stride, int rl,
                                       int k0, u16* lds, int lane) {
  int lr = lane >> 4;                               // 4 rows per instruction
  int cg2 = (lane & 15) ^ ((rl + lr) & 15);         // swizzled global chunk
  gl_lds16(tile + (size_t)(rl + lr) * stride + k0 + cg2 * 8,
           lds + (size_t)rl * 128);
}
__device__ __forceinline__ bf16x8 fragld(const u16* lds, int row, int cl) {
  return *(const bf16x8*)&lds[(size_t)row * 128 + (size_t)((cl ^ (row & 15)) << 3)];
}

// ---- Kt=64 variants (LDS row = 64 bf16 = 8x16B chunks); 8 rows per gl_lds16
__device__ __forceinline__ void stage8_64(const u16* tile, size_t stride, int rl,
                                          int k0, u16* lds, int lane) {
  int lr = lane >> 3;                               // 8 rows per instruction
  int cg2 = (lane & 7) ^ ((rl + lr) & 7);           // swizzled global chunk
  gl_lds16(tile + (size_t)(rl + lr) * stride + k0 + cg2 * 8,
           lds + (size_t)rl * 64);
}
__device__ __forceinline__ bf16x8 fragld64(const u16* lds, int row, int cl) {
  return *(const bf16x8*)&lds[(size_t)row * 64 + (size_t)((cl ^ (row & 7)) << 3)];
}

// ================= prep: one pass over X -> bucketed colsum partials,
// fct (bf16 [c][n]), fcb (bf16 [n][c]).  Col-sum atomics go to 16 buckets
// (contention 256 -> 16 per address); fold happens in gram_part.
__global__ __launch_bounds__(256) void prep_k(const float* __restrict__ Xc,
                                              const float* __restrict__ Xs,
                                              float* __restrict__ s16,
                                              u16* __restrict__ fct,
                                              u16* __restrict__ fcb) {
  int b = blockIdx.z;
  const float* X = b ? Xs : Xc;
  u16* outT = fct + (size_t)b * ((size_t)CCH * NPIX);
  __shared__ float T[64][65];
  __shared__ float red2[64][4];
  int n0 = blockIdx.x * 64, c0 = blockIdx.y * 64;
  int t = threadIdx.x;
  int cr = t & 15, nr = t >> 4;
  #pragma unroll
  for (int rr = 0; rr < 4; ++rr) {
    int n = nr + rr * 16;
    float4 v = *(const float4*)&X[(size_t)(n0 + n) * CCH + c0 + cr * 4];
    T[n][cr * 4 + 0] = v.x;
    T[n][cr * 4 + 1] = v.y;
    T[n][cr * 4 + 2] = v.z;
    T[n][cr * 4 + 3] = v.w;
    if (b == 0) {
      ushort4 q;
      q.x = f2bf(v.x); q.y = f2bf(v.y); q.z = f2bf(v.z); q.w = f2bf(v.w);
      *(ushort4*)&fcb[(size_t)(n0 + n) * CCH + c0 + cr * 4] = q;
    }
  }
  __syncthreads();
  int cl = t >> 2, np = (t & 3) * 16;
  size_t obase = (size_t)(c0 + cl) * NPIX + n0 + np;
  float s = 0.f;
  u16 ov[16];
  #pragma unroll
  for (int i = 0; i < 16; i += 4) {
    float v0 = T[np + i + 0][cl], v1 = T[np + i + 1][cl];
    float v2 = T[np + i + 2][cl], v3 = T[np + i + 3][cl];
    s += v0 + v1 + v2 + v3;
    ov[i + 0] = f2bf(v0); ov[i + 1] = f2bf(v1);
    ov[i + 2] = f2bf(v2); ov[i + 3] = f2bf(v3);
  }
  *(bf16x8*)&outT[obase + 0] = *(bf16x8*)&ov[0];   // 16B stores (obase mult of 16)
  *(bf16x8*)&outT[obase + 8] = *(bf16x8*)&ov[8];
  red2[cl][t & 3] = s;
  __syncthreads();
  if (t < 64) {
    float cs = red2[t][0] + red2[t][1] + red2[t][2] + red2[t][3];
    atomicAdd(&s16[(blockIdx.x & 15) * 1024 + b * CCH + c0 + t], cs);
  }
}

// ================= Gram partials: 16 pairs x 16 kc x 2 batches = 512 blocks = 2/CU
// K=1024 per block; 2-phase dbuf; plain stores to Gp. Block (kc=0,pair=0) also
// folds the 16-bucket colsum partials into sums (free: no extra dispatch).
__global__ __launch_bounds__(256, 2) void gram_part(const u16* __restrict__ fct,
                                                    float* __restrict__ Gp,
                                                    const float* __restrict__ s16,
                                                    float* __restrict__ sums) {
  int kc = blockIdx.x;               // 0..15, K chunk of 1024
  int pair = blockIdx.y;             // 0..15
  int b = blockIdx.z;
  int tid = threadIdx.x;
  if (kc == 0 && pair == 0) {
    // fold: sums[b][c] = sum over 16 buckets (L2-hot from prep)
    #pragma unroll
    for (int c = tid; c < CCH; c += 256) {
      float s = 0.f;
      #pragma unroll
      for (int k = 0; k < 16; ++k) s += s16[k * 1024 + b * CCH + c];
      sums[b * CCH + c] = s;
    }
  }
  int bi = pair >> 2, bj = pair & 3;
  const u16* Xb = fct + (size_t)b * ((size_t)CCH * NPIX);
  __shared__ u16 As[2][128 * 64];    // 2 x 16 KB
  __shared__ u16 Bs[2][128 * 64];    // 2 x 16 KB
  int w = tid >> 6, lane = tid & 63;
  int qm = w & 1, qn = w >> 1;
  const u16* ssrc = (w < 2) ? Xb + (size_t)(bi * 128) * NPIX
                            : Xb + (size_t)(bj * 128) * NPIX;
  int rbase = (w & 1) * 64;
  f32x4 acc[4][4];
  #pragma unroll
  for (int t = 0; t < 4; ++t)
    #pragma unroll
    for (int u = 0; u < 4; ++u) acc[t][u] = (f32x4)(0.f);

  #pragma unroll
  for (int i = 0; i < 8; ++i)
    stage8_64(ssrc, NPIX, rbase + i * 8, kc * 1024, (w < 2) ? As[0] : Bs[0], lane);
  __syncthreads();

  for (int st = 0; st < 16; ++st) {
    int cur = st & 1;
    if (st < 15) {
      int k0n = kc * 1024 + (st + 1) * 64;
      #pragma unroll
      for (int i = 0; i < 8; ++i)
        stage8_64(ssrc, NPIX, rbase + i * 8, k0n,
                  (w < 2) ? As[cur ^ 1] : Bs[cur ^ 1], lane);
    }
    #pragma unroll
    for (int s = 0; s < 2; ++s) {
      int cl = s * 4 + (lane >> 4);
      bf16x8 a[4], bb[4];
      #pragma unroll
      for (int t = 0; t < 4; ++t) a[t] = fragld64(As[cur], qm * 64 + t * 16 + (lane & 15), cl);
      #pragma unroll
      for (int u = 0; u < 4; ++u) bb[u] = fragld64(Bs[cur], qn * 64 + u * 16 + (lane & 15), cl);
      #pragma unroll
      for (int t = 0; t < 4; ++t)
        #pragma unroll
        for (int u = 0; u < 4; ++u)
          acc[t][u] = __builtin_amdgcn_mfma_f32_16x16x32_bf16(a[t], bb[u], acc[t][u], 0, 0, 0);
    }
    __syncthreads();
  }
  size_t tbase = ((size_t)(b * 16 + kc) * 16 + pair) * 16384;
  #pragma unroll
  for (int t = 0; t < 4; ++t) {
    int row0 = qm * 64 + t * 16 + (lane >> 4) * 4;
    #pragma unroll
    for (int u = 0; u < 4; ++u) {
      int col = qn * 64 + u * 16 + (lane & 15);
      #pragma unroll
      for (int r4 = 0; r4 < 4; ++r4)
        Gp[tbase + (size_t)(row0 + r4) * 128 + col] = acc[t][u][r4];
    }
  }
}

// ================= reduce partials + cov = (G - s s^T/N)/(N-1) + eps I ; rowsum |.|
__global__ __launch_bounds__(256) void gram_reduce(const float* __restrict__ Gp,
                                                   const float* __restrict__ sums,
                                                   float* __restrict__ cov,
                                                   float* __restrict__ rowsum) {
  int idx = blockIdx.x * 256 + threadIdx.x;   // 0 .. 2*MS-1
  int b = idx >> 18;
  int ij = idx & (MS - 1);
  int i = ij >> 9, j = ij & 511;
  int pair = ((i >> 7) << 2) | (j >> 7);
  int lij = ((i & 127) << 7) | (j & 127);
  size_t base = ((size_t)(b * 16) * 16 + pair) * 16384 + lij;
  float g = 0.f;
  #pragma unroll
  for (int kc = 0; kc < 16; ++kc)
    g += Gp[base + (size_t)kc * (16 * 16384)];
  const float* s = sums + b * CCH;
  float v = (g - s[i] * s[j] * (1.f / (float)NPIX)) * (1.f / (float)(NPIX - 1));
  if (i == j) v += 1e-8f;
  cov[idx] = v;
  __shared__ float red[256];
  int t = threadIdx.x;
  red[t] = fabsf(v);
  __syncthreads();
  for (int st = 128; st > 0; st >>= 1) {
    if (t < st) red[t] += red[t + st];
    __syncthreads();
  }
  if (t == 0) atomicAdd(&rowsum[b * CCH + i], red[0]);
}

// ================= NS init (+ fused norm/coef): An split; Z0 = (c/2)(3I-Â), c^2=2
__global__ __launch_bounds__(256) void nsinit_k(const float* __restrict__ cov,
                                                const float* __restrict__ rowsum,
                                                float* __restrict__ snorm,
                                                float* __restrict__ coef,
                                                u16* __restrict__ Anh,
                                                u16* __restrict__ Anl,
                                                u16* __restrict__ Z0) {
  __shared__ float red[256];
  int tid = threadIdx.x, blk = blockIdx.x;
  float m = fmaxf(rowsum[tid], rowsum[tid + 256]);
  red[tid] = m; __syncthreads();
  for (int s = 128; s > 0; s >>= 1) {
    if (tid < s) red[tid] = fmaxf(red[tid], red[tid + s]);
    __syncthreads();
  }
  float snc = red[0]; __syncthreads();
  m = fmaxf(rowsum[512 + tid], rowsum[768 + tid]);
  red[tid] = m; __syncthreads();
  for (int s = 128; s > 0; s >>= 1) {
    if (tid < s) red[tid] = fmaxf(red[tid], red[tid + s]);
    __syncthreads();
  }
  float sns = red[0];
  if (blk == 0 && tid == 0) {
    snorm[0] = snc; snorm[1] = sns;
    coef[0] = 0.8f * sqrtf(sns / snc);
  }
  int idx = blk * 256 + tid;                 // 0 .. 2*MS-1 (grid 2048)
  int b = idx >> 18;
  int ij = idx & (MS - 1);
  int diag = (ij >> 9) == (ij & 511);
  float av = cov[idx] * (b ? 1.f / sns : 1.f / snc);
  u16 hi = f2bf(av);
  Anh[idx] = hi;
  Anl[idx] = f2bf(av - b2f(hi));
  float t0 = (diag ? 3.f - av : -av) * 0.70710678f;   // boosted first step
  Z0[idx] = f2bf(t0);
}

// ================= plain bf16 NS matmul, 64x64 tiles, Kt=128 dbuf: D = diag*I + scale*(A @ B^T)
struct MM16 {
  const u16* A[4];
  const u16* B[4];
  void* D[4];
  float scale, diag;
  int outFp32;
};

__global__ __launch_bounds__(256) void mm16_k(MM16 args) {
  int z = blockIdx.z;
  const u16* __restrict__ A = args.A[z];
  const u16* __restrict__ B = args.B[z];
  int bi = blockIdx.y, bj = blockIdx.x;
  __shared__ u16 As[2][64 * 128];    // 2 x 16 KB
  __shared__ u16 Bs[2][64 * 128];    // 2 x 16 KB
  int tid = threadIdx.x, w = tid >> 6, lane = tid & 63;
  int qm = w & 1, qn = w >> 1;
  const u16* ssrc = ((w < 2) ? A + (size_t)(bi * 64) * CCH : B + (size_t)(bj * 64) * CCH);
  int rbase = (w & 1) * 32;
  f32x4 acc[2][2];
  #pragma unroll
  for (int t = 0; t < 2; ++t)
    #pragma unroll
    for (int u = 0; u < 2; ++u) acc[t][u] = (f32x4)(0.f);

  #pragma unroll
  for (int i = 0; i < 8; ++i)
    stage4(ssrc, CCH, rbase + i * 4, 0, (w < 2) ? As[0] : Bs[0], lane);
  __syncthreads();

  for (int st = 0; st < 4; ++st) {
    int cur = st & 1;
    if (st < 3) {
      #pragma unroll
      for (int i = 0; i < 8; ++i)
        stage4(ssrc, CCH, rbase + i * 4, (st + 1) * 128,
               (w < 2) ? As[cur ^ 1] : Bs[cur ^ 1], lane);
    }
    #pragma unroll
    for (int s = 0; s < 4; ++s) {
      int cl = s * 4 + (lane >> 4);
      bf16x8 a[2], bb[2];
      #pragma unroll
      for (int t = 0; t < 2; ++t) a[t] = fragld(As[cur], qm * 32 + t * 16 + (lane & 15), cl);
      #pragma unroll
      for (int u = 0; u < 2; ++u) bb[u] = fragld(Bs[cur], qn * 32 + u * 16 + (lane & 15), cl);
      #pragma unroll
      for (int t = 0; t < 2; ++t)
        #pragma unroll
        for (int u = 0; u < 2; ++u)
          acc[t][u] = __builtin_amdgcn_mfma_f32_16x16x32_bf16(a[t], bb[u], acc[t][u], 0, 0, 0);
    }
    __syncthreads();
  }
  float sc = args.scale;
  #pragma unroll
  for (int t = 0; t < 2; ++t) {
    int row0 = bi * 64 + qm * 32 + t * 16 + (lane >> 4) * 4;
    #pragma unroll
    for (int u = 0; u < 2; ++u) {
      int col = bj * 64 + qn * 32 + u * 16 + (lane & 15);
      #pragma unroll
      for (int r4 = 0; r4 < 4; ++r4) {
        float v = sc * acc[t][u][r4];
        if (row0 + r4 == col) v += args.diag;
        size_t o = (size_t)(row0 + r4) * CCH + col;
        if (args.outFp32) ((float*)args.D[z])[o] = v;
        else ((u16*)args.D[z])[o] = f2bf(v);
      }
    }
  }
}

// ================= symmetrize + split fp32 -> hi/lo bf16
__global__ __launch_bounds__(256) void symsplit_k(const float* __restrict__ src,
                                                  u16* __restrict__ hi,
                                                  u16* __restrict__ lo) {
  int b = blockIdx.y;
  int ij = blockIdx.x * 256 + threadIdx.x;   // 0..MS-1
  int i = ij >> 9, j = ij & 511;
  size_t base = (size_t)b * MS;
  float v = 0.5f * (src[base + ij] + src[base + (size_t)j * CCH + i]);
  u16 h = f2bf(v);
  hi[base + ij] = h;
  lo[base + ij] = f2bf(v - b2f(h));
}

// ================= split-bf16 matmul (~fp32 quality), 64x64 tiles, Kt=64 dbuf
struct MMS {
  const u16 *Ah[4], *Al[4], *Bh[4], *Bl[4];
  const u16 *Eh[4], *El[4];
  u16 *Dh[4], *Dl[4];
  float *D32[4];
  u16 *Db[4];
  float scale, beta;
  const float* coefPtr;
};

__global__ __launch_bounds__(256) void mmsplit_k(MMS args) {
  int z = blockIdx.z;
  int bi = blockIdx.y, bj = blockIdx.x;
  __shared__ u16 Ash[2][64 * 64], Asl[2][64 * 64];   // 4 x 8 KB
  __shared__ u16 Bsh[2][64 * 64], Bsl[2][64 * 64];   // 4 x 8 KB
  int tid = threadIdx.x, w = tid >> 6, lane = tid & 63;
  int qm = w & 1, qn = w >> 1;
  const u16* sp = (w == 0) ? args.Ah[z] : (w == 1) ? args.Al[z]
                : (w == 2) ? args.Bh[z] : args.Bl[z];
  const u16* ssrc = sp + (size_t)(((w < 2) ? bi : bj) * 64) * CCH;
  u16* sd0 = (w == 0) ? Ash[0] : (w == 1) ? Asl[0] : (w == 2) ? Bsh[0] : Bsl[0];
  u16* sd1 = (w == 0) ? Ash[1] : (w == 1) ? Asl[1] : (w == 2) ? Bsh[1] : Bsl[1];
  f32x4 acc[2][2];
  #pragma unroll
  for (int t = 0; t < 2; ++t)
    #pragma unroll
    for (int u = 0; u < 2; ++u) acc[t][u] = (f32x4)(0.f);

  #pragma unroll
  for (int i = 0; i < 8; ++i)
    stage8_64(ssrc, CCH, i * 8, 0, sd0, lane);
  __syncthreads();

  for (int st = 0; st < 8; ++st) {
    int cur = st & 1;
    if (st < 7) {
      u16* sdn = cur ? sd0 : sd1;
      #pragma unroll
      for (int i = 0; i < 8; ++i)
        stage8_64(ssrc, CCH, i * 8, (st + 1) * 64, sdn, lane);
    }
    #pragma unroll
    for (int s = 0; s < 2; ++s) {
      int cl = s * 4 + (lane >> 4);
      bf16x8 ah[2], al[2], bh[2], bl[2];
      #pragma unroll
      for (int t = 0; t < 2; ++t) {
        int row = qm * 32 + t * 16 + (lane & 15);
        ah[t] = fragld64(Ash[cur], row, cl);
        al[t] = fragld64(Asl[cur], row, cl);
      }
      #pragma unroll
      for (int u = 0; u < 2; ++u) {
        int row = qn * 32 + u * 16 + (lane & 15);
        bh[u] = fragld64(Bsh[cur], row, cl);
        bl[u] = fragld64(Bsl[cur], row, cl);
      }
      #pragma unroll
      for (int t = 0; t < 2; ++t)
        #pragma unroll
        for (int u = 0; u < 2; ++u) {
          acc[t][u] = __builtin_amdgcn_mfma_f32_16x16x32_bf16(ah[t], bh[u], acc[t][u], 0, 0, 0);
          acc[t][u] = __builtin_amdgcn_mfma_f32_16x16x32_bf16(ah[t], bl[u], acc[t][u], 0, 0, 0);
          acc[t][u] = __builtin_amdgcn_mfma_f32_16x16x32_bf16(al[t], bh[u], acc[t][u], 0, 0, 0);
        }
    }
    __syncthreads();
  }
  float sc = args.scale;
  if (args.coefPtr) sc *= *args.coefPtr;
  #pragma unroll
  for (int t = 0; t < 2; ++t) {
    int row0 = bi * 64 + qm * 32 + t * 16 + (lane >> 4) * 4;
    #pragma unroll
    for (int u = 0; u < 2; ++u) {
      int col = bj * 64 + qn * 32 + u * 16 + (lane & 15);
      #pragma unroll
      for (int r4 = 0; r4 < 4; ++r4) {
        size_t o = (size_t)(row0 + r4) * CCH + col;
        float v = sc * acc[t][u][r4];
        if (args.beta != 0.f) v += args.beta * (b2f(args.Eh[z][o]) + b2f(args.El[z][o]));
        if (args.D32[z]) args.D32[z][o] = v;
        if (args.Dh[z]) {
          u16 h = f2bf(v);
          args.Dh[z][o] = h;
          args.Dl[z][o] = f2bf(v - b2f(h));
        }
        if (args.Db[z]) args.Db[z][o] = f2bf(v);
      }
    }
  }
}

// ================= mconst[c] = (0.8*ssum[c] - (M @ csum)[c]) / N
__global__ __launch_bounds__(256) void mconst_k(const u16* __restrict__ Mb,
                                                const float* __restrict__ sums,
                                                float* __restrict__ mconst) {
  int c = blockIdx.x * 8 + (threadIdx.x >> 5);   // grid 64
  int l = threadIdx.x & 31;
  float s = 0.f;
  #pragma unroll
  for (int k = 0; k < 16; ++k) {
    int j = l + 32 * k;
    s += b2f(Mb[(size_t)c * CCH + j]) * sums[j];
  }
  s += __shfl_down(s, 16, 32);
  s += __shfl_down(s, 8, 32);
  s += __shfl_down(s, 4, 32);
  s += __shfl_down(s, 2, 32);
  s += __shfl_down(s, 1, 32);
  if (l == 0) mconst[c] = (0.8f * sums[512 + c] - s) * (1.f / (float)NPIX);
}

// ================= apply: out = fcb @ M^T + mconst + 0.2 X   (128-tiles, Kt=64 dbuf)
__global__ __launch_bounds__(256) void apply_mfma(const u16* __restrict__ fcb,
                                                  const u16* __restrict__ Mb,
                                                  const float* __restrict__ mconst,
                                                  const float* __restrict__ X,
                                                  float* __restrict__ out) {
  int bi = blockIdx.y;    // n tile (0..127)
  int bj = blockIdx.x;    // c tile (0..3)
  __shared__ u16 As[2][128 * 64];    // 2 x 16 KB
  __shared__ u16 Bs[2][128 * 64];    // 2 x 16 KB
  int tid = threadIdx.x, w = tid >> 6, lane = tid & 63;
  int qm = w & 1, qn = w >> 1;
  const u16* ssrc = (w < 2) ? fcb + (size_t)(bi * 128) * CCH
                            : Mb + (size_t)(bj * 128) * CCH;
  int rbase = (w & 1) * 64;
  f32x4 acc[4][4];
  #pragma unroll
  for (int t = 0; t < 4; ++t)
    #pragma unroll
    for (int u = 0; u < 4; ++u) acc[t][u] = (f32x4)(0.f);

  #pragma unroll
  for (int i = 0; i < 8; ++i)
    stage8_64(ssrc, CCH, rbase + i * 8, 0, (w < 2) ? As[0] : Bs[0], lane);
  __syncthreads();

  for (int st = 0; st < 8; ++st) {
    int cur = st & 1;
    if (st < 7) {
      #pragma unroll
      for (int i = 0; i < 8; ++i)
        stage8_64(ssrc, CCH, rbase + i * 8, (st + 1) * 64,
                  (w < 2) ? As[cur ^ 1] : Bs[cur ^ 1], lane);
    }
    #pragma unroll
    for (int s = 0; s < 2; ++s) {
      int cl = s * 4 + (lane >> 4);
      bf16x8 a[4], bb[4];
      #pragma unroll
      for (int t = 0; t < 4; ++t) a[t] = fragld64(As[cur], qm * 64 + t * 16 + (lane & 15), cl);
      #pragma unroll
      for (int u = 0; u < 4; ++u) bb[u] = fragld64(Bs[cur], qn * 64 + u * 16 + (lane & 15), cl);
      #pragma unroll
      for (int t = 0; t < 4; ++t)
        #pragma unroll
        for (int u = 0; u < 4; ++u)
          acc[t][u] = __builtin_amdgcn_mfma_f32_16x16x32_bf16(a[t], bb[u], acc[t][u], 0, 0, 0);
    }
    __syncthreads();
  }
  #pragma unroll
  for (int t = 0; t < 4; ++t) {
    int row0 = bi * 128 + qm * 64 + t * 16 + (lane >> 4) * 4;
    #pragma unroll
    for (int u = 0; u < 4; ++u) {
      int col = bj * 128 + qn * 64 + u * 16 + (lane & 15);
      float cst = mconst[col];
      #pragma unroll
      for (int r4 = 0; r4 < 4; ++r4) {
        size_t o = (size_t)(row0 + r4) * CCH + col;
        out[o] = acc[t][u][r4] + cst + 0.2f * X[o];
      }
    }
  }
}

// ================================================================ launcher
extern "C" void kernel_launch(void* const* d_in, const int* in_sizes, int n_in,
                              void* d_out, int out_size, void* d_ws, size_t ws_size,
                              hipStream_t stream) {
  const float* Xc = (const float*)d_in[0];
  const float* Xs = (const float*)d_in[1];
  float* out = (float*)d_out;

  float* f = (float*)d_ws;
  float* sums   = f;                     // 1024 (written by gram_part fold)
  float* rowsum = f + 1024;              // 1024
  float* s16    = f + 2048;              // 16 buckets x 1024 = 16384 (zeroed)
  float* cov    = f + 2048 + 2 * MS;     // 2*MS
  float* snorm  = cov + 2 * MS;          // 8
  float* coef   = snorm + 8;             // 8
  float* mconst = coef + 8;              // 512
  float* Zf     = mconst + 512;          // 2*MS (fp32, reused for Zr)

  // Gram split-K partials live in d_out (dead until apply_mfma): 32 MiB exactly.
  float* Gp = (float*)d_out;

  u16* h   = (u16*)(Zf + 2 * MS);
  u16* fct = h;                          // 2*512*16384 u16 (dead after gram)
  u16* fcb = h + (size_t)2 * CCH * NPIX; // 16384*512 u16
  const size_t B2 = 2 * MS;
  u16* Anh  = fct + 0 * B2;
  u16* Anl  = fct + 1 * B2;
  u16* Y1   = fct + 2 * B2;
  u16* Ya   = fct + 3 * B2;
  u16* Z0   = fct + 4 * B2;
  u16* Z1   = fct + 5 * B2;
  u16* Tb   = fct + 6 * B2;
  u16* Zfsh = fct + 7 * B2;
  u16* Zfsl = fct + 8 * B2;
  u16* Ph   = fct + 9 * B2;
  u16* Pl   = fct + 10 * B2;
  u16* Qh   = fct + 11 * B2;
  u16* Ql   = fct + 12 * B2;
  u16* Zrsh = fct + 13 * B2;
  u16* Zrsl = fct + 14 * B2;
  u16* W2h  = fct + 15 * B2;
  u16* W2l  = W2h + MS;
  u16* Mb   = W2l + MS;

  // zero: sums + rowsum + 16-bucket colsum partials
  hipMemsetAsync(d_ws, 0, (2048 + 16384) * sizeof(float), stream);

  prep_k<<<dim3(256, 8, 2), 256, 0, stream>>>(Xc, Xs, s16, fct, fcb);
  gram_part<<<dim3(16, 16, 2), 256, 0, stream>>>(fct, Gp, s16, sums);
  gram_reduce<<<2048, 256, 0, stream>>>(Gp, sums, cov, rowsum);
  nsinit_k<<<2048, 256, 0, stream>>>(cov, rowsum, snorm, coef, Anh, Anl, Z0);

  // NS: boosted first step (in nsinit) + 2 full iterations + final Z-update
  {
    MM16 y1{};
    y1.A[0] = Anh;      y1.B[0] = Z0;      y1.D[0] = Y1;
    y1.A[1] = Anh + MS; y1.B[1] = Z0 + MS; y1.D[1] = Y1 + MS;
    y1.scale = 1.f; y1.diag = 0.f; y1.outFp32 = 0;
    mm16_k<<<dim3(8, 8, 2), 256, 0, stream>>>(y1);
  }
  {
    MM16 t{};   // T0 = 3I - Z0 @ Y1
    t.A[0] = Z0;      t.B[0] = Y1;      t.D[0] = Tb;
    t.A[1] = Z0 + MS; t.B[1] = Y1 + MS; t.D[1] = Tb + MS;
    t.scale = -1.f; t.diag = 3.f; t.outFp32 = 0;
    mm16_k<<<dim3(8, 8, 2), 256, 0, stream>>>(t);
  }
  {
    MM16 yz{};  // Ya = Y1@T0/2 ; Z1 = T0@Z0/2
    yz.A[0] = Y1;      yz.B[0] = Tb;      yz.D[0] = Ya;
    yz.A[1] = Y1 + MS; yz.B[1] = Tb + MS; yz.D[1] = Ya + MS;
    yz.A[2] = Tb;      yz.B[2] = Z0;      yz.D[2] = Z1;
    yz.A[3] = Tb + MS; yz.B[3] = Z0 + MS; yz.D[3] = Z1 + MS;
    yz.scale = 0.5f; yz.diag = 0.f; yz.outFp32 = 0;
    mm16_k<<<dim3(8, 8, 4), 256, 0, stream>>>(yz);
  }
  {
    MM16 t{};   // T1 = 3I - Z1 @ Ya
    t.A[0] = Z1;      t.B[0] = Ya;      t.D[0] = Tb;
    t.A[1] = Z1 + MS; t.B[1] = Ya + MS; t.D[1] = Tb + MS;
    t.scale = -1.f; t.diag = 3.f; t.outFp32 = 0;
    mm16_k<<<dim3(8, 8, 2), 256, 0, stream>>>(t);
  }
  {
    MM16 yz{};  // Y1 = Ya@T1/2 ; Z0 = T1@Z1/2
    yz.A[0] = Ya;      yz.B[0] = Tb;      yz.D[0] = Y1;
    yz.A[1] = Ya + MS; yz.B[1] = Tb + MS; yz.D[1] = Y1 + MS;
    yz.A[2] = Tb;      yz.B[2] = Z1;      yz.D[2] = Z0;
    yz.A[3] = Tb + MS; yz.B[3] = Z1 + MS; yz.D[3] = Z0 + MS;
    yz.scale = 0.5f; yz.diag = 0.f; yz.outFp32 = 0;
    mm16_k<<<dim3(8, 8, 4), 256, 0, stream>>>(yz);
  }
  {
    MM16 t{};   // T2 = 3I - Z0 @ Y1
    t.A[0] = Z0;      t.B[0] = Y1;      t.D[0] = Tb;
    t.A[1] = Z0 + MS; t.B[1] = Y1 + MS; t.D[1] = Tb + MS;
    t.scale = -1.f; t.diag = 3.f; t.outFp32 = 0;
    mm16_k<<<dim3(8, 8, 2), 256, 0, stream>>>(t);
  }
  {
    MM16 zf{};  // Zf = T2 @ Z0 / 2  (fp32)
    zf.A[0] = Tb;      zf.B[0] = Z0;      zf.D[0] = Zf;
    zf.A[1] = Tb + MS; zf.B[1] = Z0 + MS; zf.D[1] = Zf + MS;
    zf.scale = 0.5f; zf.diag = 0.f; zf.outFp32 = 1;
    mm16_k<<<dim3(8, 8, 2), 256, 0, stream>>>(zf);
  }

  // symmetrize+split Zf
  symsplit_k<<<dim3(1024, 2), 256, 0, stream>>>(Zf, Zfsh, Zfsl);

  // P_b = Zfs_b @ An_b ; Q_b = Zfs_b @ Zfs_b
  MMS pq{};
  for (int b = 0; b < 2; ++b) {
    pq.Ah[b] = Zfsh + b * MS; pq.Al[b] = Zfsl + b * MS;
    pq.Bh[b] = Anh + b * MS;  pq.Bl[b] = Anl + b * MS;
    pq.Dh[b] = Ph + b * MS;   pq.Dl[b] = Pl + b * MS;
    pq.Ah[2 + b] = Zfsh + b * MS; pq.Al[2 + b] = Zfsl + b * MS;
    pq.Bh[2 + b] = Zfsh + b * MS; pq.Bl[2 + b] = Zfsl + b * MS;
    pq.Dh[2 + b] = Qh + b * MS;   pq.Dl[2 + b] = Ql + b * MS;
  }
  pq.scale = 1.f;
  mmsplit_k<<<dim3(8, 8, 4), 256, 0, stream>>>(pq);

  // Zr_b = 1.5 Zfs_b - 0.5 P_b @ Q_b  (fp32 out into Zf)
  MMS zr{};
  for (int b = 0; b < 2; ++b) {
    zr.Ah[b] = Ph + b * MS;   zr.Al[b] = Pl + b * MS;
    zr.Bh[b] = Qh + b * MS;   zr.Bl[b] = Ql + b * MS;
    zr.Eh[b] = Zfsh + b * MS; zr.El[b] = Zfsl + b * MS;
    zr.D32[b] = Zf + b * MS;
  }
  zr.scale = -0.5f; zr.beta = 1.5f;
  mmsplit_k<<<dim3(8, 8, 2), 256, 0, stream>>>(zr);

  // symmetrize+split Zr
  symsplit_k<<<dim3(1024, 2), 256, 0, stream>>>(Zf, Zrsh, Zrsl);

  // W2 = An_s @ Zrs_s (split out)
  MMS wv{};
  wv.Ah[0] = Anh + MS;  wv.Al[0] = Anl + MS;
  wv.Bh[0] = Zrsh + MS; wv.Bl[0] = Zrsl + MS;
  wv.Dh[0] = W2h; wv.Dl[0] = W2l;
  wv.scale = 1.f;
  mmsplit_k<<<dim3(8, 8, 1), 256, 0, stream>>>(wv);

  // M = coef * W2 @ Zrs_c (bf16 out)
  MMS mv{};
  mv.Ah[0] = W2h;  mv.Al[0] = W2l;
  mv.Bh[0] = Zrsh; mv.Bl[0] = Zrsl;
  mv.Db[0] = Mb;
  mv.scale = 1.f; mv.coefPtr = coef;
  mmsplit_k<<<dim3(8, 8, 1), 256, 0, stream>>>(mv);

  mconst_k<<<64, 256, 0, stream>>>(Mb, sums, mconst);
  apply_mfma<<<dim3(4, 128), 256, 0, stream>>>(fcb, Mb, mconst, Xc, out);
}

// Round 8
// 267.433 us; speedup vs baseline: 4.9782x; 1.0224x over previous
//
#include <hip/hip_runtime.h>
#include <math.h>

#define NPIX 16384      // H*W
#define CCH  512        // channels
#define MS   262144     // 512*512

typedef unsigned short u16;
typedef unsigned int u32;
typedef __attribute__((ext_vector_type(8))) short bf16x8;   // 8 bf16 = 4 VGPR
typedef __attribute__((ext_vector_type(4))) float f32x4;

__device__ __forceinline__ u16 f2bf(float f) {
  u32 u = __builtin_bit_cast(u32, f);
  u += 0x7fffu + ((u >> 16) & 1u);    // round-to-nearest-even
  return (u16)(u >> 16);
}
__device__ __forceinline__ float b2f(u16 h) {
  u32 u = ((u32)h) << 16;
  return __builtin_bit_cast(float, u);
}

typedef const __attribute__((address_space(1))) u32* gp_t;
typedef __attribute__((address_space(3))) u32* lp_t;
__device__ __forceinline__ void gl_lds16(const void* g, void* l) {
  __builtin_amdgcn_global_load_lds((gp_t)g, (lp_t)l, 16, 0, 0);
}

// ---- Kt=128 staged tile, XOR chunk swizzle (LDS row = 128 bf16 = 16x16B chunks)
__device__ __forceinline__ void stage4(const u16* tile, size_t stride, int rl,
                                       int k0, u16* lds, int lane) {
  int lr = lane >> 4;                               // 4 rows per instruction
  int cg2 = (lane & 15) ^ ((rl + lr) & 15);         // swizzled global chunk
  gl_lds16(tile + (size_t)(rl + lr) * stride + k0 + cg2 * 8,
           lds + (size_t)rl * 128);
}
__device__ __forceinline__ bf16x8 fragld(const u16* lds, int row, int cl) {
  return *(const bf16x8*)&lds[(size_t)row * 128 + (size_t)((cl ^ (row & 15)) << 3)];
}

// ---- Kt=64 variants (LDS row = 64 bf16 = 8x16B chunks); 8 rows per gl_lds16
__device__ __forceinline__ void stage8_64(const u16* tile, size_t stride, int rl,
                                          int k0, u16* lds, int lane) {
  int lr = lane >> 3;                               // 8 rows per instruction
  int cg2 = (lane & 7) ^ ((rl + lr) & 7);           // swizzled global chunk
  gl_lds16(tile + (size_t)(rl + lr) * stride + k0 + cg2 * 8,
           lds + (size_t)rl * 64);
}
__device__ __forceinline__ bf16x8 fragld64(const u16* lds, int row, int cl) {
  return *(const bf16x8*)&lds[(size_t)row * 64 + (size_t)((cl ^ (row & 7)) << 3)];
}

// ================= prep: one pass over X -> bucketed colsum partials,
// fct (bf16 [c][n]), fcb (bf16 [n][c]).
__global__ __launch_bounds__(256) void prep_k(const float* __restrict__ Xc,
                                              const float* __restrict__ Xs,
                                              float* __restrict__ s16,
                                              u16* __restrict__ fct,
                                              u16* __restrict__ fcb) {
  int b = blockIdx.z;
  const float* X = b ? Xs : Xc;
  u16* outT = fct + (size_t)b * ((size_t)CCH * NPIX);
  __shared__ float T[64][65];
  __shared__ float red2[64][4];
  int n0 = blockIdx.x * 64, c0 = blockIdx.y * 64;
  int t = threadIdx.x;
  int cr = t & 15, nr = t >> 4;
  #pragma unroll
  for (int rr = 0; rr < 4; ++rr) {
    int n = nr + rr * 16;
    float4 v = *(const float4*)&X[(size_t)(n0 + n) * CCH + c0 + cr * 4];
    T[n][cr * 4 + 0] = v.x;
    T[n][cr * 4 + 1] = v.y;
    T[n][cr * 4 + 2] = v.z;
    T[n][cr * 4 + 3] = v.w;
    if (b == 0) {
      ushort4 q;
      q.x = f2bf(v.x); q.y = f2bf(v.y); q.z = f2bf(v.z); q.w = f2bf(v.w);
      *(ushort4*)&fcb[(size_t)(n0 + n) * CCH + c0 + cr * 4] = q;
    }
  }
  __syncthreads();
  int cl = t >> 2, np = (t & 3) * 16;
  size_t obase = (size_t)(c0 + cl) * NPIX + n0 + np;
  float s = 0.f;
  u16 ov[16];
  #pragma unroll
  for (int i = 0; i < 16; i += 4) {
    float v0 = T[np + i + 0][cl], v1 = T[np + i + 1][cl];
    float v2 = T[np + i + 2][cl], v3 = T[np + i + 3][cl];
    s += v0 + v1 + v2 + v3;
    ov[i + 0] = f2bf(v0); ov[i + 1] = f2bf(v1);
    ov[i + 2] = f2bf(v2); ov[i + 3] = f2bf(v3);
  }
  *(bf16x8*)&outT[obase + 0] = *(bf16x8*)&ov[0];   // 16B stores
  *(bf16x8*)&outT[obase + 8] = *(bf16x8*)&ov[8];
  red2[cl][t & 3] = s;
  __syncthreads();
  if (t < 64) {
    float cs = red2[t][0] + red2[t][1] + red2[t][2] + red2[t][3];
    atomicAdd(&s16[(blockIdx.x & 15) * 1024 + b * CCH + c0 + t], cs);
  }
}

// ================= Gram partials: 16 pairs x 16 kc x 2 batches = 512 blocks = 2/CU
__global__ __launch_bounds__(256, 2) void gram_part(const u16* __restrict__ fct,
                                                    float* __restrict__ Gp,
                                                    const float* __restrict__ s16,
                                                    float* __restrict__ sums) {
  int kc = blockIdx.x;               // 0..15, K chunk of 1024
  int pair = blockIdx.y;             // 0..15
  int b = blockIdx.z;
  int tid = threadIdx.x;
  if (kc == 0 && pair == 0) {
    #pragma unroll
    for (int c = tid; c < CCH; c += 256) {
      float s = 0.f;
      #pragma unroll
      for (int k = 0; k < 16; ++k) s += s16[k * 1024 + b * CCH + c];
      sums[b * CCH + c] = s;
    }
  }
  int bi = pair >> 2, bj = pair & 3;
  const u16* Xb = fct + (size_t)b * ((size_t)CCH * NPIX);
  __shared__ u16 As[2][128 * 64];    // 2 x 16 KB
  __shared__ u16 Bs[2][128 * 64];    // 2 x 16 KB
  int w = tid >> 6, lane = tid & 63;
  int qm = w & 1, qn = w >> 1;
  const u16* ssrc = (w < 2) ? Xb + (size_t)(bi * 128) * NPIX
                            : Xb + (size_t)(bj * 128) * NPIX;
  int rbase = (w & 1) * 64;
  f32x4 acc[4][4];
  #pragma unroll
  for (int t = 0; t < 4; ++t)
    #pragma unroll
    for (int u = 0; u < 4; ++u) acc[t][u] = (f32x4)(0.f);

  #pragma unroll
  for (int i = 0; i < 8; ++i)
    stage8_64(ssrc, NPIX, rbase + i * 8, kc * 1024, (w < 2) ? As[0] : Bs[0], lane);
  __syncthreads();

  for (int st = 0; st < 16; ++st) {
    int cur = st & 1;
    if (st < 15) {
      int k0n = kc * 1024 + (st + 1) * 64;
      #pragma unroll
      for (int i = 0; i < 8; ++i)
        stage8_64(ssrc, NPIX, rbase + i * 8, k0n,
                  (w < 2) ? As[cur ^ 1] : Bs[cur ^ 1], lane);
    }
    #pragma unroll
    for (int s = 0; s < 2; ++s) {
      int cl = s * 4 + (lane >> 4);
      bf16x8 a[4], bb[4];
      #pragma unroll
      for (int t = 0; t < 4; ++t) a[t] = fragld64(As[cur], qm * 64 + t * 16 + (lane & 15), cl);
      #pragma unroll
      for (int u = 0; u < 4; ++u) bb[u] = fragld64(Bs[cur], qn * 64 + u * 16 + (lane & 15), cl);
      #pragma unroll
      for (int t = 0; t < 4; ++t)
        #pragma unroll
        for (int u = 0; u < 4; ++u)
          acc[t][u] = __builtin_amdgcn_mfma_f32_16x16x32_bf16(a[t], bb[u], acc[t][u], 0, 0, 0);
    }
    __syncthreads();
  }
  size_t tbase = ((size_t)(b * 16 + kc) * 16 + pair) * 16384;
  #pragma unroll
  for (int t = 0; t < 4; ++t) {
    int row0 = qm * 64 + t * 16 + (lane >> 4) * 4;
    #pragma unroll
    for (int u = 0; u < 4; ++u) {
      int col = qn * 64 + u * 16 + (lane & 15);
      #pragma unroll
      for (int r4 = 0; r4 < 4; ++r4)
        Gp[tbase + (size_t)(row0 + r4) * 128 + col] = acc[t][u][r4];
    }
  }
}

// ================= reduce partials + cov = (G - s s^T/N)/(N-1) + eps I ; rowsum |.|
__global__ __launch_bounds__(256) void gram_reduce(const float* __restrict__ Gp,
                                                   const float* __restrict__ sums,
                                                   float* __restrict__ cov,
                                                   float* __restrict__ rowsum) {
  int idx = blockIdx.x * 256 + threadIdx.x;   // 0 .. 2*MS-1
  int b = idx >> 18;
  int ij = idx & (MS - 1);
  int i = ij >> 9, j = ij & 511;
  int pair = ((i >> 7) << 2) | (j >> 7);
  int lij = ((i & 127) << 7) | (j & 127);
  size_t base = ((size_t)(b * 16) * 16 + pair) * 16384 + lij;
  float g = 0.f;
  #pragma unroll
  for (int kc = 0; kc < 16; ++kc)
    g += Gp[base + (size_t)kc * (16 * 16384)];
  const float* s = sums + b * CCH;
  float v = (g - s[i] * s[j] * (1.f / (float)NPIX)) * (1.f / (float)(NPIX - 1));
  if (i == j) v += 1e-8f;
  cov[idx] = v;
  __shared__ float red[256];
  int t = threadIdx.x;
  red[t] = fabsf(v);
  __syncthreads();
  for (int st = 128; st > 0; st >>= 1) {
    if (t < st) red[t] += red[t + st];
    __syncthreads();
  }
  if (t == 0) atomicAdd(&rowsum[b * CCH + i], red[0]);
}

// ================= NS init (+ fused norm/coef): An split; Z0 = (c/2)(3I-Â), c^2=2
__global__ __launch_bounds__(256) void nsinit_k(const float* __restrict__ cov,
                                                const float* __restrict__ rowsum,
                                                float* __restrict__ snorm,
                                                float* __restrict__ coef,
                                                u16* __restrict__ Anh,
                                                u16* __restrict__ Anl,
                                                u16* __restrict__ Z0) {
  __shared__ float red[256];
  int tid = threadIdx.x, blk = blockIdx.x;
  float m = fmaxf(rowsum[tid], rowsum[tid + 256]);
  red[tid] = m; __syncthreads();
  for (int s = 128; s > 0; s >>= 1) {
    if (tid < s) red[tid] = fmaxf(red[tid], red[tid + s]);
    __syncthreads();
  }
  float snc = red[0]; __syncthreads();
  m = fmaxf(rowsum[512 + tid], rowsum[768 + tid]);
  red[tid] = m; __syncthreads();
  for (int s = 128; s > 0; s >>= 1) {
    if (tid < s) red[tid] = fmaxf(red[tid], red[tid + s]);
    __syncthreads();
  }
  float sns = red[0];
  if (blk == 0 && tid == 0) {
    snorm[0] = snc; snorm[1] = sns;
    coef[0] = 0.8f * sqrtf(sns / snc);
  }
  int idx = blk * 256 + tid;                 // 0 .. 2*MS-1 (grid 2048)
  int b = idx >> 18;
  int ij = idx & (MS - 1);
  int diag = (ij >> 9) == (ij & 511);
  float av = cov[idx] * (b ? 1.f / sns : 1.f / snc);
  u16 hi = f2bf(av);
  Anh[idx] = hi;
  Anl[idx] = f2bf(av - b2f(hi));
  float t0 = (diag ? 3.f - av : -av) * 0.70710678f;   // boosted first step
  Z0[idx] = f2bf(t0);
}

// ================= plain bf16 NS matmul, 32x64 tiles (2x fill), Kt=128 dbuf:
// D = diag*I + scale*(A @ B^T).  Grid (8 bj, 16 bi, z).
// Per-element k-order identical to the 64x64 version -> bit-identical output.
struct MM16 {
  const u16* A[4];
  const u16* B[4];
  void* D[4];
  float scale, diag;
  int outFp32;
};

__global__ __launch_bounds__(256) void mm16_k(MM16 args) {
  int z = blockIdx.z;
  const u16* __restrict__ A = args.A[z];
  const u16* __restrict__ B = args.B[z];
  int bi = blockIdx.y, bj = blockIdx.x;   // bi: 32-row tile (0..15), bj: 64-col (0..7)
  __shared__ u16 As[2][32 * 128];    // 2 x 8 KB
  __shared__ u16 Bs[2][64 * 128];    // 2 x 16 KB  (total 48 KB)
  int tid = threadIdx.x, w = tid >> 6, lane = tid & 63;
  int qm = w & 1, qn = w >> 1;
  // staging: w0/w1 -> A halves (16 rows each), w2/w3 -> B halves (32 rows each)
  const u16* ssrc = (w < 2) ? A + (size_t)(bi * 32) * CCH
                            : B + (size_t)(bj * 64) * CCH;
  int rbase = (w < 2) ? (w & 1) * 16 : (w & 1) * 32;
  f32x4 acc[2];
  acc[0] = (f32x4)(0.f); acc[1] = (f32x4)(0.f);

  if (w < 2) {
    #pragma unroll
    for (int i = 0; i < 4; ++i) stage4(ssrc, CCH, rbase + i * 4, 0, As[0], lane);
  } else {
    #pragma unroll
    for (int i = 0; i < 8; ++i) stage4(ssrc, CCH, rbase + i * 4, 0, Bs[0], lane);
  }
  __syncthreads();

  for (int st = 0; st < 4; ++st) {
    int cur = st & 1;
    if (st < 3) {
      int k0 = (st + 1) * 128;
      if (w < 2) {
        #pragma unroll
        for (int i = 0; i < 4; ++i) stage4(ssrc, CCH, rbase + i * 4, k0, As[cur ^ 1], lane);
      } else {
        #pragma unroll
        for (int i = 0; i < 8; ++i) stage4(ssrc, CCH, rbase + i * 4, k0, Bs[cur ^ 1], lane);
      }
    }
    #pragma unroll
    for (int s = 0; s < 4; ++s) {
      int cl = s * 4 + (lane >> 4);
      bf16x8 a = fragld(As[cur], qm * 16 + (lane & 15), cl);
      bf16x8 b0 = fragld(Bs[cur], qn * 32 + (lane & 15), cl);
      bf16x8 b1 = fragld(Bs[cur], qn * 32 + 16 + (lane & 15), cl);
      acc[0] = __builtin_amdgcn_mfma_f32_16x16x32_bf16(a, b0, acc[0], 0, 0, 0);
      acc[1] = __builtin_amdgcn_mfma_f32_16x16x32_bf16(a, b1, acc[1], 0, 0, 0);
    }
    __syncthreads();
  }
  float sc = args.scale;
  int row0 = bi * 32 + qm * 16 + (lane >> 4) * 4;
  #pragma unroll
  for (int u = 0; u < 2; ++u) {
    int col = bj * 64 + qn * 32 + u * 16 + (lane & 15);
    #pragma unroll
    for (int r4 = 0; r4 < 4; ++r4) {
      float v = sc * acc[u][r4];
      if (row0 + r4 == col) v += args.diag;
      size_t o = (size_t)(row0 + r4) * CCH + col;
      if (args.outFp32) ((float*)args.D[z])[o] = v;
      else ((u16*)args.D[z])[o] = f2bf(v);
    }
  }
}

// ================= symmetrize + split fp32 -> hi/lo bf16
__global__ __launch_bounds__(256) void symsplit_k(const float* __restrict__ src,
                                                  u16* __restrict__ hi,
                                                  u16* __restrict__ lo) {
  int b = blockIdx.y;
  int ij = blockIdx.x * 256 + threadIdx.x;   // 0..MS-1
  int i = ij >> 9, j = ij & 511;
  size_t base = (size_t)b * MS;
  float v = 0.5f * (src[base + ij] + src[base + (size_t)j * CCH + i]);
  u16 h = f2bf(v);
  hi[base + ij] = h;
  lo[base + ij] = f2bf(v - b2f(h));
}

// ================= split-bf16 matmul, 32x64 tiles (2x fill), Kt=64 dbuf.
// Grid (8 bj, 16 bi, z).  Same triad order per element -> bit-identical.
struct MMS {
  const u16 *Ah[4], *Al[4], *Bh[4], *Bl[4];
  const u16 *Eh[4], *El[4];
  u16 *Dh[4], *Dl[4];
  float *D32[4];
  u16 *Db[4];
  float scale, beta;
  const float* coefPtr;
};

__global__ __launch_bounds__(256) void mmsplit_k(MMS args) {
  int z = blockIdx.z;
  int bi = blockIdx.y, bj = blockIdx.x;   // bi: 32-row (0..15), bj: 64-col (0..7)
  __shared__ u16 Ash[2][32 * 64], Asl[2][32 * 64];   // 4 x 4 KB
  __shared__ u16 Bsh[2][64 * 64], Bsl[2][64 * 64];   // 4 x 8 KB  (total 48 KB)
  int tid = threadIdx.x, w = tid >> 6, lane = tid & 63;
  int qm = w & 1, qn = w >> 1;
  // w0 stages Ah (32 rows), w1 Al, w2 Bh (64 rows), w3 Bl
  const u16* sp = (w == 0) ? args.Ah[z] : (w == 1) ? args.Al[z]
                : (w == 2) ? args.Bh[z] : args.Bl[z];
  const u16* ssrc = sp + (size_t)(((w < 2) ? bi * 32 : bj * 64)) * CCH;
  u16* sd0 = (w == 0) ? Ash[0] : (w == 1) ? Asl[0] : (w == 2) ? Bsh[0] : Bsl[0];
  u16* sd1 = (w == 0) ? Ash[1] : (w == 1) ? Asl[1] : (w == 2) ? Bsh[1] : Bsl[1];
  int nst = (w < 2) ? 4 : 8;
  f32x4 acc[2];
  acc[0] = (f32x4)(0.f); acc[1] = (f32x4)(0.f);

  for (int i = 0; i < nst; ++i)
    stage8_64(ssrc, CCH, i * 8, 0, sd0, lane);
  __syncthreads();

  for (int st = 0; st < 8; ++st) {
    int cur = st & 1;
    if (st < 7) {
      u16* sdn = cur ? sd0 : sd1;
      for (int i = 0; i < nst; ++i)
        stage8_64(ssrc, CCH, i * 8, (st + 1) * 64, sdn, lane);
    }
    #pragma unroll
    for (int s = 0; s < 2; ++s) {
      int cl = s * 4 + (lane >> 4);
      int arow = qm * 16 + (lane & 15);
      bf16x8 ah = fragld64(Ash[cur], arow, cl);
      bf16x8 al = fragld64(Asl[cur], arow, cl);
      bf16x8 bh[2], bl[2];
      #pragma unroll
      for (int u = 0; u < 2; ++u) {
        int brow = qn * 32 + u * 16 + (lane & 15);
        bh[u] = fragld64(Bsh[cur], brow, cl);
        bl[u] = fragld64(Bsl[cur], brow, cl);
      }
      #pragma unroll
      for (int u = 0; u < 2; ++u) {
        acc[u] = __builtin_amdgcn_mfma_f32_16x16x32_bf16(ah, bh[u], acc[u], 0, 0, 0);
        acc[u] = __builtin_amdgcn_mfma_f32_16x16x32_bf16(ah, bl[u], acc[u], 0, 0, 0);
        acc[u] = __builtin_amdgcn_mfma_f32_16x16x32_bf16(al, bh[u], acc[u], 0, 0, 0);
      }
    }
    __syncthreads();
  }
  float sc = args.scale;
  if (args.coefPtr) sc *= *args.coefPtr;
  int row0 = bi * 32 + qm * 16 + (lane >> 4) * 4;
  #pragma unroll
  for (int u = 0; u < 2; ++u) {
    int col = bj * 64 + qn * 32 + u * 16 + (lane & 15);
    #pragma unroll
    for (int r4 = 0; r4 < 4; ++r4) {
      size_t o = (size_t)(row0 + r4) * CCH + col;
      float v = sc * acc[u][r4];
      if (args.beta != 0.f) v += args.beta * (b2f(args.Eh[z][o]) + b2f(args.El[z][o]));
      if (args.D32[z]) args.D32[z][o] = v;
      if (args.Dh[z]) {
        u16 h = f2bf(v);
        args.Dh[z][o] = h;
        args.Dl[z][o] = f2bf(v - b2f(h));
      }
      if (args.Db[z]) args.Db[z][o] = f2bf(v);
    }
  }
}

// ================= mconst[c] = (0.8*ssum[c] - (M @ csum)[c]) / N
__global__ __launch_bounds__(256) void mconst_k(const u16* __restrict__ Mb,
                                                const float* __restrict__ sums,
                                                float* __restrict__ mconst) {
  int c = blockIdx.x * 8 + (threadIdx.x >> 5);   // grid 64
  int l = threadIdx.x & 31;
  float s = 0.f;
  #pragma unroll
  for (int k = 0; k < 16; ++k) {
    int j = l + 32 * k;
    s += b2f(Mb[(size_t)c * CCH + j]) * sums[j];
  }
  s += __shfl_down(s, 16, 32);
  s += __shfl_down(s, 8, 32);
  s += __shfl_down(s, 4, 32);
  s += __shfl_down(s, 2, 32);
  s += __shfl_down(s, 1, 32);
  if (l == 0) mconst[c] = (0.8f * sums[512 + c] - s) * (1.f / (float)NPIX);
}

// ================= apply: out = fcb @ M^T + mconst + 0.2 X   (128-tiles, Kt=64 dbuf)
__global__ __launch_bounds__(256) void apply_mfma(const u16* __restrict__ fcb,
                                                  const u16* __restrict__ Mb,
                                                  const float* __restrict__ mconst,
                                                  const float* __restrict__ X,
                                                  float* __restrict__ out) {
  int bi = blockIdx.y;    // n tile (0..127)
  int bj = blockIdx.x;    // c tile (0..3)
  __shared__ u16 As[2][128 * 64];    // 2 x 16 KB
  __shared__ u16 Bs[2][128 * 64];    // 2 x 16 KB
  int tid = threadIdx.x, w = tid >> 6, lane = tid & 63;
  int qm = w & 1, qn = w >> 1;
  const u16* ssrc = (w < 2) ? fcb + (size_t)(bi * 128) * CCH
                            : Mb + (size_t)(bj * 128) * CCH;
  int rbase = (w & 1) * 64;
  f32x4 acc[4][4];
  #pragma unroll
  for (int t = 0; t < 4; ++t)
    #pragma unroll
    for (int u = 0; u < 4; ++u) acc[t][u] = (f32x4)(0.f);

  #pragma unroll
  for (int i = 0; i < 8; ++i)
    stage8_64(ssrc, CCH, rbase + i * 8, 0, (w < 2) ? As[0] : Bs[0], lane);
  __syncthreads();

  for (int st = 0; st < 8; ++st) {
    int cur = st & 1;
    if (st < 7) {
      #pragma unroll
      for (int i = 0; i < 8; ++i)
        stage8_64(ssrc, CCH, rbase + i * 8, (st + 1) * 64,
                  (w < 2) ? As[cur ^ 1] : Bs[cur ^ 1], lane);
    }
    #pragma unroll
    for (int s = 0; s < 2; ++s) {
      int cl = s * 4 + (lane >> 4);
      bf16x8 a[4], bb[4];
      #pragma unroll
      for (int t = 0; t < 4; ++t) a[t] = fragld64(As[cur], qm * 64 + t * 16 + (lane & 15), cl);
      #pragma unroll
      for (int u = 0; u < 4; ++u) bb[u] = fragld64(Bs[cur], qn * 64 + u * 16 + (lane & 15), cl);
      #pragma unroll
      for (int t = 0; t < 4; ++t)
        #pragma unroll
        for (int u = 0; u < 4; ++u)
          acc[t][u] = __builtin_amdgcn_mfma_f32_16x16x32_bf16(a[t], bb[u], acc[t][u], 0, 0, 0);
    }
    __syncthreads();
  }
  #pragma unroll
  for (int t = 0; t < 4; ++t) {
    int row0 = bi * 128 + qm * 64 + t * 16 + (lane >> 4) * 4;
    #pragma unroll
    for (int u = 0; u < 4; ++u) {
      int col = bj * 128 + qn * 64 + u * 16 + (lane & 15);
      float cst = mconst[col];
      #pragma unroll
      for (int r4 = 0; r4 < 4; ++r4) {
        size_t o = (size_t)(row0 + r4) * CCH + col;
        out[o] = acc[t][u][r4] + cst + 0.2f * X[o];
      }
    }
  }
}

// ================================================================ launcher
extern "C" void kernel_launch(void* const* d_in, const int* in_sizes, int n_in,
                              void* d_out, int out_size, void* d_ws, size_t ws_size,
                              hipStream_t stream) {
  const float* Xc = (const float*)d_in[0];
  const float* Xs = (const float*)d_in[1];
  float* out = (float*)d_out;

  float* f = (float*)d_ws;
  float* sums   = f;                     // 1024 (written by gram_part fold)
  float* rowsum = f + 1024;              // 1024
  float* s16    = f + 2048;              // 16 buckets x 1024 = 16384 (zeroed)
  float* cov    = f + 2048 + 2 * MS;     // 2*MS
  float* snorm  = cov + 2 * MS;          // 8
  float* coef   = snorm + 8;             // 8
  float* mconst = coef + 8;              // 512
  float* Zf     = mconst + 512;          // 2*MS (fp32, reused for Zr)

  // Gram split-K partials live in d_out (dead until apply_mfma): 32 MiB exactly.
  float* Gp = (float*)d_out;

  u16* h   = (u16*)(Zf + 2 * MS);
  u16* fct = h;                          // 2*512*16384 u16 (dead after gram)
  u16* fcb = h + (size_t)2 * CCH * NPIX; // 16384*512 u16
  const size_t B2 = 2 * MS;
  u16* Anh  = fct + 0 * B2;
  u16* Anl  = fct + 1 * B2;
  u16* Y1   = fct + 2 * B2;
  u16* Ya   = fct + 3 * B2;
  u16* Z0   = fct + 4 * B2;
  u16* Z1   = fct + 5 * B2;
  u16* Tb   = fct + 6 * B2;
  u16* Zfsh = fct + 7 * B2;
  u16* Zfsl = fct + 8 * B2;
  u16* Ph   = fct + 9 * B2;
  u16* Pl   = fct + 10 * B2;
  u16* Qh   = fct + 11 * B2;
  u16* Ql   = fct + 12 * B2;
  u16* Zrsh = fct + 13 * B2;
  u16* Zrsl = fct + 14 * B2;
  u16* W2h  = fct + 15 * B2;
  u16* W2l  = W2h + MS;
  u16* Mb   = W2l + MS;

  // zero: sums + rowsum + 16-bucket colsum partials
  hipMemsetAsync(d_ws, 0, (2048 + 16384) * sizeof(float), stream);

  prep_k<<<dim3(256, 8, 2), 256, 0, stream>>>(Xc, Xs, s16, fct, fcb);
  gram_part<<<dim3(16, 16, 2), 256, 0, stream>>>(fct, Gp, s16, sums);
  gram_reduce<<<2048, 256, 0, stream>>>(Gp, sums, cov, rowsum);
  nsinit_k<<<2048, 256, 0, stream>>>(cov, rowsum, snorm, coef, Anh, Anl, Z0);

  // NS: boosted first step (in nsinit) + 2 full iterations + final Z-update
  // All matmuls now 32x64 tiles: grid (8, 16, z)
  {
    MM16 y1{};
    y1.A[0] = Anh;      y1.B[0] = Z0;      y1.D[0] = Y1;
    y1.A[1] = Anh + MS; y1.B[1] = Z0 + MS; y1.D[1] = Y1 + MS;
    y1.scale = 1.f; y1.diag = 0.f; y1.outFp32 = 0;
    mm16_k<<<dim3(8, 16, 2), 256, 0, stream>>>(y1);
  }
  {
    MM16 t{};   // T0 = 3I - Z0 @ Y1
    t.A[0] = Z0;      t.B[0] = Y1;      t.D[0] = Tb;
    t.A[1] = Z0 + MS; t.B[1] = Y1 + MS; t.D[1] = Tb + MS;
    t.scale = -1.f; t.diag = 3.f; t.outFp32 = 0;
    mm16_k<<<dim3(8, 16, 2), 256, 0, stream>>>(t);
  }
  {
    MM16 yz{};  // Ya = Y1@T0/2 ; Z1 = T0@Z0/2
    yz.A[0] = Y1;      yz.B[0] = Tb;      yz.D[0] = Ya;
    yz.A[1] = Y1 + MS; yz.B[1] = Tb + MS; yz.D[1] = Ya + MS;
    yz.A[2] = Tb;      yz.B[2] = Z0;      yz.D[2] = Z1;
    yz.A[3] = Tb + MS; yz.B[3] = Z0 + MS; yz.D[3] = Z1 + MS;
    yz.scale = 0.5f; yz.diag = 0.f; yz.outFp32 = 0;
    mm16_k<<<dim3(8, 16, 4), 256, 0, stream>>>(yz);
  }
  {
    MM16 t{};   // T1 = 3I - Z1 @ Ya
    t.A[0] = Z1;      t.B[0] = Ya;      t.D[0] = Tb;
    t.A[1] = Z1 + MS; t.B[1] = Ya + MS; t.D[1] = Tb + MS;
    t.scale = -1.f; t.diag = 3.f; t.outFp32 = 0;
    mm16_k<<<dim3(8, 16, 2), 256, 0, stream>>>(t);
  }
  {
    MM16 yz{};  // Y1 = Ya@T1/2 ; Z0 = T1@Z1/2
    yz.A[0] = Ya;      yz.B[0] = Tb;      yz.D[0] = Y1;
    yz.A[1] = Ya + MS; yz.B[1] = Tb + MS; yz.D[1] = Y1 + MS;
    yz.A[2] = Tb;      yz.B[2] = Z1;      yz.D[2] = Z0;
    yz.A[3] = Tb + MS; yz.B[3] = Z1 + MS; yz.D[3] = Z0 + MS;
    yz.scale = 0.5f; yz.diag = 0.f; yz.outFp32 = 0;
    mm16_k<<<dim3(8, 16, 4), 256, 0, stream>>>(yz);
  }
  {
    MM16 t{};   // T2 = 3I - Z0 @ Y1
    t.A[0] = Z0;      t.B[0] = Y1;      t.D[0] = Tb;
    t.A[1] = Z0 + MS; t.B[1] = Y1 + MS; t.D[1] = Tb + MS;
    t.scale = -1.f; t.diag = 3.f; t.outFp32 = 0;
    mm16_k<<<dim3(8, 16, 2), 256, 0, stream>>>(t);
  }
  {
    MM16 zf{};  // Zf = T2 @ Z0 / 2  (fp32)
    zf.A[0] = Tb;      zf.B[0] = Z0;      zf.D[0] = Zf;
    zf.A[1] = Tb + MS; zf.B[1] = Z0 + MS; zf.D[1] = Zf + MS;
    zf.scale = 0.5f; zf.diag = 0.f; zf.outFp32 = 1;
    mm16_k<<<dim3(8, 16, 2), 256, 0, stream>>>(zf);
  }

  // symmetrize+split Zf
  symsplit_k<<<dim3(1024, 2), 256, 0, stream>>>(Zf, Zfsh, Zfsl);

  // P_b = Zfs_b @ An_b ; Q_b = Zfs_b @ Zfs_b
  MMS pq{};
  for (int b = 0; b < 2; ++b) {
    pq.Ah[b] = Zfsh + b * MS; pq.Al[b] = Zfsl + b * MS;
    pq.Bh[b] = Anh + b * MS;  pq.Bl[b] = Anl + b * MS;
    pq.Dh[b] = Ph + b * MS;   pq.Dl[b] = Pl + b * MS;
    pq.Ah[2 + b] = Zfsh + b * MS; pq.Al[2 + b] = Zfsl + b * MS;
    pq.Bh[2 + b] = Zfsh + b * MS; pq.Bl[2 + b] = Zfsl + b * MS;
    pq.Dh[2 + b] = Qh + b * MS;   pq.Dl[2 + b] = Ql + b * MS;
  }
  pq.scale = 1.f;
  mmsplit_k<<<dim3(8, 16, 4), 256, 0, stream>>>(pq);

  // Zr_b = 1.5 Zfs_b - 0.5 P_b @ Q_b  (fp32 out into Zf)
  MMS zr{};
  for (int b = 0; b < 2; ++b) {
    zr.Ah[b] = Ph + b * MS;   zr.Al[b] = Pl + b * MS;
    zr.Bh[b] = Qh + b * MS;   zr.Bl[b] = Ql + b * MS;
    zr.Eh[b] = Zfsh + b * MS; zr.El[b] = Zfsl + b * MS;
    zr.D32[b] = Zf + b * MS;
  }
  zr.scale = -0.5f; zr.beta = 1.5f;
  mmsplit_k<<<dim3(8, 16, 2), 256, 0, stream>>>(zr);

  // symmetrize+split Zr
  symsplit_k<<<dim3(1024, 2), 256, 0, stream>>>(Zf, Zrsh, Zrsl);

  // W2 = An_s @ Zrs_s (split out)
  MMS wv{};
  wv.Ah[0] = Anh + MS;  wv.Al[0] = Anl + MS;
  wv.Bh[0] = Zrsh + MS; wv.Bl[0] = Zrsl + MS;
  wv.Dh[0] = W2h; wv.Dl[0] = W2l;
  wv.scale = 1.f;
  mmsplit_k<<<dim3(8, 16, 1), 256, 0, stream>>>(wv);

  // M = coef * W2 @ Zrs_c (bf16 out)
  MMS mv{};
  mv.Ah[0] = W2h;  mv.Al[0] = W2l;
  mv.Bh[0] = Zrsh; mv.Bl[0] = Zrsl;
  mv.Db[0] = Mb;
  mv.scale = 1.f; mv.coefPtr = coef;
  mmsplit_k<<<dim3(8, 16, 1), 256, 0, stream>>>(mv);

  mconst_k<<<64, 256, 0, stream>>>(Mb, sums, mconst);
  apply_mfma<<<dim3(4, 128), 256, 0, stream>>>(fcb, Mb, mconst, Xc, out);
}